// Round 1
// baseline (933.769 us; speedup 1.0000x reference)
//
#include <hip/hip_runtime.h>

#define NN 100000
#define NP 100096          // 782 * 128, padded row count
#define EE 300000
#define DIN 128
#define HD  256
#define HD2 512
#define NL  4
#define NG  512
#define BN_EPS 1e-5f

typedef __attribute__((ext_vector_type(8))) short s8v;      // bf16x8 frag (4 VGPRs)
typedef __attribute__((ext_vector_type(4))) float f4v;      // fp32x4 acc

typedef unsigned short ushort_t;

// float -> bf16, round-to-nearest-even
static __device__ inline ushort_t f2bf(float f) {
    unsigned u = __float_as_uint(f);
    unsigned r = (u + 0x7fffu + ((u >> 16) & 1u)) >> 16;
    return (ushort_t)r;
}
static __device__ inline float bf2f(ushort_t h) {
    return __uint_as_float(((unsigned)h) << 16);
}
// bf16 pair unpack from packed u32: low half needs shift, high half mask-only
static __device__ inline float blo(unsigned v) { return __uint_as_float(v << 16); }
static __device__ inline float bhi(unsigned v) { return __uint_as_float(v & 0xffff0000u); }

// async global->LDS, 16B per lane; LDS dest = uniform base + lane*16
#define GLOAD_LDS16(g, l) __builtin_amdgcn_global_load_lds( \
    (const __attribute__((address_space(1))) unsigned int*)(const void*)(g), \
    (__attribute__((address_space(3))) unsigned int*)(void*)(l), 16, 0, 0)

// s_waitcnt immediates: vmcnt[3:0] | expcnt(7)<<4 | lgkmcnt(15)<<8 | vmcnt[5:4]<<14
#define WAITCNT_VM8 0xF78
#define WAITCNT_VM4 0xF74
#define WAITCNT_VM0 0xF70

// ---------------------------------------------------------------------------
// bf16 MFMA GEMM (kept for GEMM0 / input projection only).
// Block tile 128x128, BK=32, 4 waves, 3-stage circular LDS pipeline.
// ---------------------------------------------------------------------------
__global__ __launch_bounds__(256) void gemm_bf16(
    const ushort_t* __restrict__ A, int lda,
    const ushort_t* __restrict__ BT, int ldb,
    const float* __restrict__ bias,
    ushort_t* __restrict__ C, int ldc,
    int K, int doRelu,
    int doStats, float* __restrict__ stats, int Mvalid)
{
    extern __shared__ char smem[];
    ushort_t* lds = (ushort_t*)smem;            // 3 stages x (A 8KB | B 8KB)
    ushort_t* Cs  = lds;                        // epilogue reuse (32 KB)
    float* ssum   = (float*)(smem + 49152);     // [4][128]
    float* ssq    = ssum + 512;

    const int tid  = threadIdx.x;
    const int w    = tid >> 6;
    const int L    = tid & 63;
    const int lm   = L & 15;
    const int q    = L >> 4;
    const int row0 = blockIdx.x * 128;
    const int col0 = blockIdx.y * 128;

    const ushort_t* gAbase = A  + (size_t)lm * lda;
    const ushort_t* gBbase = BT + (size_t)lm * ldb;

    f4v acc[2][8] = {};

    const int niter = K >> 5;

    #define STAGE(buf, k0) do {                                              \
        ushort_t* As_ = lds + (buf) * 8192;                                  \
        ushort_t* Bs_ = As_ + 4096;                                          \
        const int kk_ = (k0) + q * 8;                                        \
        _Pragma("unroll")                                                    \
        for (int i_ = 0; i_ < 2; ++i_) {                                     \
            const int tl_ = w * 2 + i_;                                      \
            GLOAD_LDS16(gAbase + (size_t)(row0 + tl_ * 16) * lda + kk_,      \
                        As_ + tl_ * 512);                                    \
            GLOAD_LDS16(gBbase + (size_t)(col0 + tl_ * 16) * ldb + kk_,      \
                        Bs_ + tl_ * 512);                                    \
        }                                                                    \
    } while (0)

    STAGE(0, 0);
    if (niter > 1) STAGE(1, 32);
    if (niter > 2) STAGE(2, 64);

    int cur = 0;
    for (int it = 0; it < niter; ++it) {
        const int rem = niter - 1 - it;
        if (rem >= 2)      __builtin_amdgcn_s_waitcnt(WAITCNT_VM8);
        else if (rem == 1) __builtin_amdgcn_s_waitcnt(WAITCNT_VM4);
        else               __builtin_amdgcn_s_waitcnt(WAITCNT_VM0);
        __builtin_amdgcn_s_barrier();

        const ushort_t* Ab = lds + cur * 8192;
        const ushort_t* Bb = Ab + 4096;
        s8v a0 = *(const s8v*)&Ab[(2 * w)     * 512 + L * 8];
        s8v a1 = *(const s8v*)&Ab[(2 * w + 1) * 512 + L * 8];
#pragma unroll
        for (int nt = 0; nt < 8; ++nt) {
            s8v b = *(const s8v*)&Bb[nt * 512 + L * 8];
            acc[0][nt] = __builtin_amdgcn_mfma_f32_16x16x32_bf16(a0, b, acc[0][nt], 0, 0, 0);
            acc[1][nt] = __builtin_amdgcn_mfma_f32_16x16x32_bf16(a1, b, acc[1][nt], 0, 0, 0);
        }
        __builtin_amdgcn_s_barrier();
        if (it + 3 < niter) STAGE(cur, (it + 3) * 32);
        cur = (cur == 2) ? 0 : cur + 1;
    }
    #undef STAGE

    __syncthreads();

    // epilogue: bias + relu + cvt; C/D frag: col = lm, row = q*4 + r
    float cs[8] = {};
    float cq[8] = {};
#pragma unroll
    for (int mt = 0; mt < 2; ++mt) {
#pragma unroll
        for (int nt = 0; nt < 8; ++nt) {
            const float bj = bias[col0 + nt * 16 + lm];
            f4v v = acc[mt][nt];
#pragma unroll
            for (int r = 0; r < 4; ++r) {
                float f = v[r] + bj;
                if (doRelu) f = fmaxf(f, 0.f);
                const int row = (2 * w + mt) * 16 + q * 4 + r;
                const int col = nt * 16 + lm;
                Cs[row * 128 + col] = f2bf(f);
                if (doStats && (row0 + row) < Mvalid) {
                    cs[nt] += f;
                    cq[nt] += f * f;
                }
            }
        }
    }
    if (doStats) {
#pragma unroll
        for (int nt = 0; nt < 8; ++nt) {
            float s = cs[nt], sq = cq[nt];
            s  += __shfl_xor(s, 16, 64);  s  += __shfl_xor(s, 32, 64);
            sq += __shfl_xor(sq, 16, 64); sq += __shfl_xor(sq, 32, 64);
            cs[nt] = s; cq[nt] = sq;
        }
    }
    __syncthreads();
    if (doStats && q == 0) {
#pragma unroll
        for (int nt = 0; nt < 8; ++nt) {
            ssum[w * 128 + nt * 16 + lm] = cs[nt];
            ssq [w * 128 + nt * 16 + lm] = cq[nt];
        }
    }
#pragma unroll
    for (int i = 0; i < 8; ++i) {
        const int idx = i * 256 + tid;
        const int row = idx >> 4, ch = idx & 15;
        s8v val = *(const s8v*)&Cs[row * 128 + ch * 8];
        *(s8v*)(C + (size_t)(row0 + row) * ldc + col0 + ch * 8) = val;
    }
    if (doStats) {
        __syncthreads();
        if (tid < 128) {
            const float s  = ssum[tid] + ssum[128 + tid] + ssum[256 + tid] + ssum[384 + tid];
            const float sq = ssq[tid]  + ssq[128 + tid]  + ssq[256 + tid]  + ssq[384 + tid];
            unsafeAtomicAdd(&stats[col0 + tid], s);
            unsafeAtomicAdd(&stats[HD + col0 + tid], sq);
        }
    }
}

// ---------------------------------------------------------------------------
// Fused GIN MLP: z = (agg @ W1 + b1).relu() @ W2 + b2, plus column stats.
// Removes the 102 MB hidden write + 102 MB read per layer (the two
// latency-bound 77 us GEMMs become one kernel).
//
// Structure: 128 rows/block, 8 waves (512 thr), 1 block/CU.
//  - Each wave owns 16 rows; its A slice (16x256 bf16) lives in 32 VGPRs.
//  - Loop over 8 hidden-chunks of 64 cols:
//      stage W1-chunk (32KB) + W2-chunk (32KB) into double-buffered LDS
//      (global_load_lds x16B, issued right after the barrier => a full
//       chunk (~512 block MFMAs) of latency cover);
//      GEMM1: acc1[4] = A x W1c (32 MFMA/wave);
//      bias+relu+cvt -> wave-private XOR-swizzled LDS hchunk [16][64] bf16
//      (the frag transpose; no cross-wave sync, compiler lgkmcnt only);
//      GEMM2: zacc[16] += hchunk x W2c (32 MFMA/wave).
//  - One vmcnt(0)+barrier per chunk: 512 MFMAs/barrier block-wide vs 64
//    in the old per-GEMM pipeline.
// LDS: 2 x 64KB W stages + 8 x 2KB hchunk = 144 KB (1 block/CU; HK attn
// precedent runs 160 KB blocks on gfx950).
// ---------------------------------------------------------------------------
__global__ __launch_bounds__(512, 2) void fused_mlp_kernel(
    const ushort_t* __restrict__ A,      // [NP, HD] bf16 (aggregate out)
    const ushort_t* __restrict__ W1l,    // [HD2, HD] bf16, out-major (B^T)
    const float*    __restrict__ b1l,    // [HD2]
    const ushort_t* __restrict__ W2l,    // [HD, HD2] bf16, out-major (B^T)
    const float*    __restrict__ b2l,    // [HD]
    ushort_t* __restrict__ C,            // [NP, HD] bf16 (pre-BN z)
    float* __restrict__ stats)           // [2*HD] col sum / sumsq (atomic)
{
    extern __shared__ char smem[];
    ushort_t* lds = (ushort_t*)smem;
    const int tid = threadIdx.x;
    const int w   = tid >> 6;            // wave 0..7 -> rows [w*16, w*16+16)
    const int L   = tid & 63;
    const int lm  = L & 15;
    const int q   = L >> 4;
    const int row0 = blockIdx.x * 128;

    // ---- A slice in registers: a[kk] = A-frag for k-step kk (K=256) ----
    const ushort_t* Arow = A + (size_t)(row0 + w * 16 + lm) * HD;
    s8v a[8];
#pragma unroll
    for (int kk = 0; kk < 8; ++kk)
        a[kk] = *(const s8v*)(Arow + kk * 32 + q * 8);

    // wave-private hidden chunk [16 rows][64 cols] bf16, XOR-swizzled:
    // byte = (r*128 + c*2) ^ ((r&7)<<4)  (row-octet spread over banks)
    char* hcb = smem + 131072 + w * 2048;

    // stage a 64-col hidden chunk of weights: W1c 16x(16r x 32k) units,
    // W2c 16x(16n x 32k) units; 1 KB per unit, lane-linear LDS.
    // waves 0..3 stage W1 (32 units), waves 4..7 stage W2 (32 units).
#define STAGE_W(buf, cb_) do {                                                \
    ushort_t* Wb_ = lds + (buf) * 32768;                                      \
    if (w < 4) {                                                              \
        _Pragma("unroll")                                                     \
        for (int i_ = 0; i_ < 8; ++i_) {                                      \
            const int u_ = w * 8 + i_;                                        \
            const int kk_ = u_ >> 2, nt_ = u_ & 3;                            \
            GLOAD_LDS16(W1l + (size_t)((cb_) + nt_ * 16 + lm) * HD + kk_ * 32 + q * 8, \
                        Wb_ + u_ * 512);                                      \
        }                                                                     \
    } else {                                                                  \
        _Pragma("unroll")                                                     \
        for (int i_ = 0; i_ < 8; ++i_) {                                      \
            const int u_ = (w - 4) * 8 + i_;                                  \
            const int ks_ = u_ >> 4, nt_ = u_ & 15;                           \
            GLOAD_LDS16(W2l + (size_t)(nt_ * 16 + lm) * HD2 + (cb_) + ks_ * 32 + q * 8, \
                        Wb_ + 16384 + u_ * 512);                              \
        }                                                                     \
    }                                                                         \
} while (0)

    STAGE_W(0, 0);

    f4v acc2[16] = {};                   // z rows w*16.. x 256 cols
#pragma unroll
    for (int c = 0; c < 8; ++c) {
        __builtin_amdgcn_s_waitcnt(WAITCNT_VM0);   // stage(c) landed
        __builtin_amdgcn_s_barrier();
        if (c < 7) STAGE_W((c + 1) & 1, (c + 1) * 64);  // ~512 MFMAs of cover

        const ushort_t* Wb  = lds + (c & 1) * 32768;
        const ushort_t* W2b = Wb + 16384;

        // GEMM1: hchunk = A x W1c  (4 independent acc chains over nt)
        f4v acc1[4] = {};
#pragma unroll
        for (int kk = 0; kk < 8; ++kk) {
#pragma unroll
            for (int nt = 0; nt < 4; ++nt) {
                s8v b = *(const s8v*)&Wb[(kk * 4 + nt) * 512 + L * 8];
                acc1[nt] = __builtin_amdgcn_mfma_f32_16x16x32_bf16(a[kk], b, acc1[nt], 0, 0, 0);
            }
        }
        // bias + relu + bf16 -> swizzled wave-private LDS (frag transpose)
#pragma unroll
        for (int nt = 0; nt < 4; ++nt) {
            const float bj = b1l[c * 64 + nt * 16 + lm];
#pragma unroll
            for (int r = 0; r < 4; ++r) {
                const int rr  = q * 4 + r;
                const int byo = (rr * 128 + (nt * 16 + lm) * 2) ^ ((rr & 7) << 4);
                *(ushort_t*)(hcb + byo) = f2bf(fmaxf(acc1[nt][r] + bj, 0.f));
            }
        }
        // GEMM2: zacc += hchunk x W2c  (16 independent chains over nt)
#pragma unroll
        for (int ks = 0; ks < 2; ++ks) {
            const int rb = (lm * 128 + ks * 64 + q * 16) ^ ((lm & 7) << 4);
            const s8v at = *(const s8v*)(hcb + rb);
#pragma unroll
            for (int nt = 0; nt < 16; ++nt) {
                s8v b = *(const s8v*)&W2b[(ks * 16 + nt) * 512 + L * 8];
                acc2[nt] = __builtin_amdgcn_mfma_f32_16x16x32_bf16(at, b, acc2[nt], 0, 0, 0);
            }
        }
    }
#undef STAGE_W

    __syncthreads();

    // ---- epilogue: bias + stats + bf16, LDS bounce for coalesced store ----
    float* ssum  = (float*)smem;             // [8][256]  bytes 0..8K
    float* ssq   = (float*)(smem + 8192);    // [8][256]  bytes 8K..16K
    ushort_t* Cs = lds + 8192;               // [128][256] bf16, bytes 16K..80K

#pragma unroll
    for (int nt = 0; nt < 16; ++nt) {
        const float bj = b2l[nt * 16 + lm];
        float s = 0.f, sq = 0.f;
#pragma unroll
        for (int r = 0; r < 4; ++r) {
            const float f  = acc2[nt][r] + bj;
            const int row  = w * 16 + q * 4 + r;
            Cs[row * 256 + nt * 16 + lm] = f2bf(f);
            if (row0 + row < NN) { s += f; sq += f * f; }
        }
        s  += __shfl_xor(s, 16, 64);  s  += __shfl_xor(s, 32, 64);
        sq += __shfl_xor(sq, 16, 64); sq += __shfl_xor(sq, 32, 64);
        if (q == 0) {
            ssum[w * 256 + nt * 16 + lm] = s;
            ssq [w * 256 + nt * 16 + lm] = sq;
        }
    }
    __syncthreads();

#pragma unroll
    for (int i = 0; i < 8; ++i) {
        const int idx = i * 512 + tid;       // 16B unit among 4096
        const int row = idx >> 5, ch = idx & 31;
        const s8v v = *(const s8v*)&Cs[idx * 8];
        *(s8v*)(C + (size_t)(row0 + row) * HD + ch * 8) = v;
    }
    if (tid < HD) {
        float s = 0.f, sq = 0.f;
#pragma unroll
        for (int ww = 0; ww < 8; ++ww) {
            s  += ssum[ww * 256 + tid];
            sq += ssq [ww * 256 + tid];
        }
        unsafeAtomicAdd(&stats[tid], s);
        unsafeAtomicAdd(&stats[HD + tid], sq);
    }
}

// ---------------------------------------------------------------------------
// Batched transpose + fp32->bf16: out[z][c][r] = in[z][r][c]; blockIdx.z = batch.
__global__ __launch_bounds__(256) void transpose_cvt_kernel(
    const float* __restrict__ in, ushort_t* __restrict__ out, int R, int C,
    long inStride, long outStride)
{
    __shared__ float tile[32][33];
    const float* inp  = in  + (size_t)blockIdx.z * inStride;
    ushort_t*    outp = out + (size_t)blockIdx.z * outStride;
    const int bx = blockIdx.x * 32;
    const int by = blockIdx.y * 32;
    const int tx = threadIdx.x & 31;
    const int ty = threadIdx.x >> 5;
#pragma unroll
    for (int i = 0; i < 32; i += 8)
        tile[ty + i][tx] = inp[(size_t)(by + ty + i) * C + bx + tx];
    __syncthreads();
#pragma unroll
    for (int i = 0; i < 32; i += 8)
        outp[(size_t)(bx + ty + i) * R + by + tx] = f2bf(tile[tx][ty + i]);
}

__global__ __launch_bounds__(256) void cvt_kernel(
    const float* __restrict__ in, ushort_t* __restrict__ out, long n4)
{
    const long i = (long)blockIdx.x * 256 + threadIdx.x;
    if (i >= n4) return;
    const float4 v = ((const float4*)in)[i];
    ushort4 o;
    o.x = f2bf(v.x); o.y = f2bf(v.y); o.z = f2bf(v.z); o.w = f2bf(v.w);
    ((ushort4*)out)[i] = o;
}

__global__ __launch_bounds__(256) void zero_kernel(float* __restrict__ p, long n4)
{
    const long i = (long)blockIdx.x * 256 + threadIdx.x;
    if (i < n4) ((float4*)p)[i] = make_float4(0.f, 0.f, 0.f, 0.f);
}

// identity scale/shift + zeroed stats (once per call, before layer 0)
__global__ __launch_bounds__(256) void init_bn_kernel(
    float* __restrict__ sscale, float* __restrict__ sshift,
    float* __restrict__ stats)
{
    const int t = threadIdx.x;
    sscale[t] = 1.f;
    sshift[t] = 0.f;
    stats[t] = 0.f;
    stats[HD + t] = 0.f;
}

// scale/shift from stats; re-zero stats for the next layer
__global__ __launch_bounds__(256) void bnprep_kernel(
    float* __restrict__ stats, const float* __restrict__ gamma,
    const float* __restrict__ beta, float* __restrict__ sscale,
    float* __restrict__ sshift, int Nn)
{
    const int t = threadIdx.x;
    const float invN = 1.0f / (float)Nn;
    const float mu  = stats[t] * invN;
    const float var = stats[HD + t] * invN - mu * mu;
    const float inv = rsqrtf(var + BN_EPS);
    const float sc  = gamma[t] * inv;
    sscale[t] = sc;
    sshift[t] = beta[t] - mu * sc;
    stats[t] = 0.f;
    stats[HD + t] = 0.f;
}

// ---------------- CSR build (per call; edges are layer-invariant) -----------
__global__ __launch_bounds__(256) void hist_kernel(
    const int* __restrict__ dst, int* __restrict__ deg, int E)
{
    const int e = blockIdx.x * 256 + threadIdx.x;
    if (e < E) atomicAdd(&deg[dst[e]], 1);
}

__global__ __launch_bounds__(256) void scan1_kernel(
    const int* __restrict__ deg, int* __restrict__ partial,
    int* __restrict__ bsums, int n)
{
    __shared__ int tmp[256];
    const int i = blockIdx.x * 256 + threadIdx.x;
    const int v = (i < n) ? deg[i] : 0;
    tmp[threadIdx.x] = v;
    __syncthreads();
    for (int off = 1; off < 256; off <<= 1) {
        const int t = (threadIdx.x >= off) ? tmp[threadIdx.x - off] : 0;
        __syncthreads();
        tmp[threadIdx.x] += t;
        __syncthreads();
    }
    if (i < n) partial[i] = tmp[threadIdx.x] - v;
    if (threadIdx.x == 255) bsums[blockIdx.x] = tmp[255];
}

__global__ __launch_bounds__(512) void scan2_kernel(int* __restrict__ bsums, int nb)
{
    __shared__ int tmp[512];
    const int i = threadIdx.x;
    const int v = (i < nb) ? bsums[i] : 0;
    tmp[i] = v;
    __syncthreads();
    for (int off = 1; off < 512; off <<= 1) {
        const int t = (i >= off) ? tmp[i - off] : 0;
        __syncthreads();
        tmp[i] += t;
        __syncthreads();
    }
    if (i < nb) bsums[i] = tmp[i] - v;
}

__global__ __launch_bounds__(256) void scan3_kernel(
    const int* __restrict__ partial, const int* __restrict__ bsums,
    int* __restrict__ offs, int* __restrict__ cursor, int n)
{
    const int i = blockIdx.x * 256 + threadIdx.x;
    if (i < n) {
        const int o = partial[i] + bsums[blockIdx.x];
        offs[i] = o;
        cursor[i] = o;
    }
}

__global__ __launch_bounds__(256) void scatter_kernel(
    const int* __restrict__ src, const int* __restrict__ dst,
    int* __restrict__ cursor, int* __restrict__ srcSorted, int E)
{
    const int e = blockIdx.x * 256 + threadIdx.x;
    if (e >= E) return;
    const int p = atomicAdd(&cursor[dst[e]], 1);
    srcSorted[p] = src[e];
}

// ---------------------------------------------------------------------------
// out[n] = bf16( (1+eps)*y[n] + sum_{s in nbrs(n)} y[s] ),
// y[i] = relu( z[i]*sscale + sshift )  (BN on the fly).
__global__ __launch_bounds__(256) void aggregate_kernel(
    const ushort_t* __restrict__ z, const int* __restrict__ offs,
    const int* __restrict__ deg, const int* __restrict__ srcSorted,
    const float* __restrict__ epsArr, int epsIdx,
    const float* __restrict__ sscale, const float* __restrict__ sshift,
    ushort_t* __restrict__ out)
{
    const int n = blockIdx.x * 8 + (threadIdx.x >> 5);   // 8 nodes / 256 thr
    const int L = threadIdx.x & 31;
    const int c0 = L * 8;
    const float4 scA = *(const float4*)(sscale + c0);
    const float4 scB = *(const float4*)(sscale + c0 + 4);
    const float4 shA = *(const float4*)(sshift + c0);
    const float4 shB = *(const float4*)(sshift + c0 + 4);
    const int start = offs[n];
    const int dc = deg[n];
    float a[8] = {};
    float b[8] = {};
    int j = 0;
    for (; j + 1 < dc; j += 2) {
        const int s0 = srcSorted[start + j];
        const int s1 = srcSorted[start + j + 1];
        const uint4 u = *(const uint4*)(z + (size_t)s0 * HD + c0);
        const uint4 v = *(const uint4*)(z + (size_t)s1 * HD + c0);
        a[0] += fmaxf(blo(u.x) * scA.x + shA.x, 0.f);
        a[1] += fmaxf(bhi(u.x) * scA.y + shA.y, 0.f);
        a[2] += fmaxf(blo(u.y) * scA.z + shA.z, 0.f);
        a[3] += fmaxf(bhi(u.y) * scA.w + shA.w, 0.f);
        a[4] += fmaxf(blo(u.z) * scB.x + shB.x, 0.f);
        a[5] += fmaxf(bhi(u.z) * scB.y + shB.y, 0.f);
        a[6] += fmaxf(blo(u.w) * scB.z + shB.z, 0.f);
        a[7] += fmaxf(bhi(u.w) * scB.w + shB.w, 0.f);
        b[0] += fmaxf(blo(v.x) * scA.x + shA.x, 0.f);
        b[1] += fmaxf(bhi(v.x) * scA.y + shA.y, 0.f);
        b[2] += fmaxf(blo(v.y) * scA.z + shA.z, 0.f);
        b[3] += fmaxf(bhi(v.y) * scA.w + shA.w, 0.f);
        b[4] += fmaxf(blo(v.z) * scB.x + shB.x, 0.f);
        b[5] += fmaxf(bhi(v.z) * scB.y + shB.y, 0.f);
        b[6] += fmaxf(blo(v.w) * scB.z + shB.z, 0.f);
        b[7] += fmaxf(bhi(v.w) * scB.w + shB.w, 0.f);
    }
    if (j < dc) {
        const int s0 = srcSorted[start + j];
        const uint4 u = *(const uint4*)(z + (size_t)s0 * HD + c0);
        a[0] += fmaxf(blo(u.x) * scA.x + shA.x, 0.f);
        a[1] += fmaxf(bhi(u.x) * scA.y + shA.y, 0.f);
        a[2] += fmaxf(blo(u.y) * scA.z + shA.z, 0.f);
        a[3] += fmaxf(bhi(u.y) * scA.w + shA.w, 0.f);
        a[4] += fmaxf(blo(u.z) * scB.x + shB.x, 0.f);
        a[5] += fmaxf(bhi(u.z) * scB.y + shB.y, 0.f);
        a[6] += fmaxf(blo(u.w) * scB.z + shB.z, 0.f);
        a[7] += fmaxf(bhi(u.w) * scB.w + shB.w, 0.f);
    }
#pragma unroll
    for (int k = 0; k < 8; ++k) a[k] += b[k];
    const float se = 1.0f + epsArr[epsIdx];
    const uint4 hs = *(const uint4*)(z + (size_t)n * HD + c0);
    float y[8];
    y[0] = se * fmaxf(blo(hs.x) * scA.x + shA.x, 0.f) + a[0];
    y[1] = se * fmaxf(bhi(hs.x) * scA.y + shA.y, 0.f) + a[1];
    y[2] = se * fmaxf(blo(hs.y) * scA.z + shA.z, 0.f) + a[2];
    y[3] = se * fmaxf(bhi(hs.y) * scA.w + shA.w, 0.f) + a[3];
    y[4] = se * fmaxf(blo(hs.z) * scB.x + shB.x, 0.f) + a[4];
    y[5] = se * fmaxf(bhi(hs.z) * scB.y + shB.y, 0.f) + a[5];
    y[6] = se * fmaxf(blo(hs.w) * scB.z + shB.z, 0.f) + a[6];
    y[7] = se * fmaxf(bhi(hs.w) * scB.w + shB.w, 0.f) + a[7];
    uint4 o;
    o.x = (unsigned)f2bf(y[0]) | ((unsigned)f2bf(y[1]) << 16);
    o.y = (unsigned)f2bf(y[2]) | ((unsigned)f2bf(y[3]) << 16);
    o.z = (unsigned)f2bf(y[4]) | ((unsigned)f2bf(y[5]) << 16);
    o.w = (unsigned)f2bf(y[6]) | ((unsigned)f2bf(y[7]) << 16);
    *(uint4*)(out + (size_t)n * HD + c0) = o;
}

// ---------------------------------------------------------------------------
// Fused mean-pool + head, BN on the fly.
__global__ __launch_bounds__(256) void pool_head_kernel(
    const ushort_t* __restrict__ z, const int* __restrict__ batch,
    const float* __restrict__ sscale, const float* __restrict__ sshift,
    const float* __restrict__ Wp1, const float* __restrict__ bp1,
    const float* __restrict__ Wp2, const float* __restrict__ bp2,
    float* __restrict__ out)
{
    __shared__ float poolw[4][HD];
    __shared__ float pool[HD];
    __shared__ float red[128];
    __shared__ int seg[2];
    const int g = blockIdx.x;
    const int t = threadIdx.x;
    const int w = t >> 6;
    const int L = t & 63;
    if (t == 0) {
        int lo = 0, hi = NN;
        while (lo < hi) { const int m = (lo + hi) >> 1; if (batch[m] < g) lo = m + 1; else hi = m; }
        seg[0] = lo;
        hi = NN;
        while (lo < hi) { const int m = (lo + hi) >> 1; if (batch[m] < g + 1) lo = m + 1; else hi = m; }
        seg[1] = lo;
    }
    __syncthreads();
    const int start = seg[0], end = seg[1];
    const int c0 = L * 4;
    const float4 sc = *(const float4*)(sscale + c0);
    const float4 sh = *(const float4*)(sshift + c0);
    float a0 = 0.f, a1 = 0.f, a2 = 0.f, a3 = 0.f;
    float b0 = 0.f, b1 = 0.f, b2 = 0.f, b3 = 0.f;
    int r = start + w;
    for (; r + 4 < end; r += 8) {
        const ushort4 u = *(const ushort4*)(z + (size_t)r * HD + c0);
        const ushort4 v = *(const ushort4*)(z + (size_t)(r + 4) * HD + c0);
        a0 += fmaxf(bf2f(u.x) * sc.x + sh.x, 0.f);
        a1 += fmaxf(bf2f(u.y) * sc.y + sh.y, 0.f);
        a2 += fmaxf(bf2f(u.z) * sc.z + sh.z, 0.f);
        a3 += fmaxf(bf2f(u.w) * sc.w + sh.w, 0.f);
        b0 += fmaxf(bf2f(v.x) * sc.x + sh.x, 0.f);
        b1 += fmaxf(bf2f(v.y) * sc.y + sh.y, 0.f);
        b2 += fmaxf(bf2f(v.z) * sc.z + sh.z, 0.f);
        b3 += fmaxf(bf2f(v.w) * sc.w + sh.w, 0.f);
    }
    if (r < end) {
        const ushort4 u = *(const ushort4*)(z + (size_t)r * HD + c0);
        a0 += fmaxf(bf2f(u.x) * sc.x + sh.x, 0.f);
        a1 += fmaxf(bf2f(u.y) * sc.y + sh.y, 0.f);
        a2 += fmaxf(bf2f(u.z) * sc.z + sh.z, 0.f);
        a3 += fmaxf(bf2f(u.w) * sc.w + sh.w, 0.f);
    }
    poolw[w][c0 + 0] = a0 + b0;
    poolw[w][c0 + 1] = a1 + b1;
    poolw[w][c0 + 2] = a2 + b2;
    poolw[w][c0 + 3] = a3 + b3;
    __syncthreads();
    const float invC = 1.0f / (float)max(end - start, 1);
    pool[t] = (poolw[0][t] + poolw[1][t] + poolw[2][t] + poolw[3][t]) * invC;
    __syncthreads();
    if (t < 128) {
        float acc = 0.f;
#pragma unroll 4
        for (int k = 0; k < HD; ++k)
            acc += pool[k] * Wp1[k * 128 + t];
        red[t] = fmaxf(acc + bp1[t], 0.f) * Wp2[t];
    }
    __syncthreads();
    for (int sft = 64; sft > 0; sft >>= 1) {
        if (t < sft) red[t] += red[t + sft];
        __syncthreads();
    }
    if (t == 0) out[g] = red[0] + bp2[0];
}

// ---------------------------------------------------------------------------
extern "C" void kernel_launch(void* const* d_in, const int* in_sizes, int n_in,
                              void* d_out, int out_size, void* d_ws, size_t ws_size,
                              hipStream_t stream)
{
    const float* x     = (const float*)d_in[0];
    const int*   ei    = (const int*)  d_in[1];
    const int*   batch = (const int*)  d_in[2];
    const float* W_in  = (const float*)d_in[3];
    const float* b_in  = (const float*)d_in[4];
    const float* eps   = (const float*)d_in[5];
    const float* W1    = (const float*)d_in[6];
    const float* b1    = (const float*)d_in[7];
    const float* W2    = (const float*)d_in[8];
    const float* b2    = (const float*)d_in[9];
    const float* gamma = (const float*)d_in[10];
    const float* beta  = (const float*)d_in[11];
    const float* Wp1   = (const float*)d_in[12];
    const float* bp1   = (const float*)d_in[13];
    const float* Wp2   = (const float*)d_in[14];
    const float* bp2   = (const float*)d_in[15];

    const int* srcIdx = ei;
    const int* dstIdx = ei + EE;

    // ---- workspace layout ----
    char* p = (char*)d_ws;
    ushort_t* zbuf    = (ushort_t*)p;  p += (size_t)NP * HD  * 2;   // pre-BN acts
    ushort_t* abuf    = (ushort_t*)p;  p += (size_t)NP * HD  * 2;   // aggregate out
    ushort_t* hidden  = (ushort_t*)p;  p += (size_t)NP * HD2 * 2;   // x_bf alias (GEMM0 A)
    ushort_t* W1T     = (ushort_t*)p;  p += (size_t)NL * HD2 * HD * 2;
    ushort_t* W2T     = (ushort_t*)p;  p += (size_t)NL * HD * HD2 * 2;
    ushort_t* WinT    = (ushort_t*)p;  p += (size_t)HD * DIN * 2;
    int* deg          = (int*)p;       p += (size_t)NN * 4;
    int* partial      = (int*)p;       p += (size_t)NN * 4;
    int* bsums        = (int*)p;       p += 512 * 4;
    int* offs         = (int*)p;       p += (size_t)NN * 4;
    int* cursor       = (int*)p;       p += (size_t)NN * 4;
    int* srcSorted    = (int*)p;       p += (size_t)EE * 4;
    float* stats      = (float*)p;     p += 2 * HD * 4;
    float* sscale     = (float*)p;     p += HD * 4;
    float* sshift     = (float*)p;     p += HD * 4;
    ushort_t* x_bf    = hidden;        // GEMM0 A

    const int nb = (NN + 255) / 256;   // 391
    const int GEMM_LDS  = 53248;       // gemm_bf16: 3 x 16KB stages + 4KB stats
    const int FUSED_LDS = 147456;      // fused_mlp: 2 x 64KB W stages + 16KB hchunk

    // ---- BN identity + stats zero ----
    init_bn_kernel<<<1, 256, 0, stream>>>(sscale, sshift, stats);

    // ---- weight conversion (bf16, transposed; layer-batched) ----
    transpose_cvt_kernel<<<dim3(HD / 32, DIN / 32, 1), 256, 0, stream>>>(
        W_in, WinT, DIN, HD, 0, 0);
    transpose_cvt_kernel<<<dim3(HD2 / 32, HD / 32, NL), 256, 0, stream>>>(
        W1, W1T, HD, HD2, (long)HD * HD2, (long)HD2 * HD);
    transpose_cvt_kernel<<<dim3(HD / 32, HD2 / 32, NL), 256, 0, stream>>>(
        W2, W2T, HD2, HD, (long)HD2 * HD, (long)HD * HD2);
    cvt_kernel<<<(int)(((long)NN * DIN / 4 + 255) / 256), 256, 0, stream>>>(
        x, x_bf, (long)NN * DIN / 4);

    // ---- CSR build (once; edges layer-invariant) ----
    zero_kernel<<<(NN / 4 + 255) / 256, 256, 0, stream>>>((float*)deg, NN / 4);
    hist_kernel<<<(EE + 255) / 256, 256, 0, stream>>>(dstIdx, deg, EE);
    scan1_kernel<<<nb, 256, 0, stream>>>(deg, partial, bsums, NN);
    scan2_kernel<<<1, 512, 0, stream>>>(bsums, nb);
    scan3_kernel<<<nb, 256, 0, stream>>>(partial, bsums, offs, cursor, NN);
    scatter_kernel<<<(EE + 255) / 256, 256, 0, stream>>>(srcIdx, dstIdx, cursor, srcSorted, EE);

    // ---- input projection: zbuf = relu(x @ W_in + b_in)  (identity BN) ----
    gemm_bf16<<<dim3(NP / 128, HD / 128), 256, GEMM_LDS, stream>>>(
        x_bf, DIN, WinT, DIN, b_in, zbuf, HD, DIN, 1, 0, nullptr, 0);

    // ---- GIN layers: aggregate -> fused MLP (+stats) -> BN prep ----
    for (int l = 0; l < NL; ++l) {
        aggregate_kernel<<<NN / 8, 256, 0, stream>>>(
            zbuf, offs, deg, srcSorted, eps, l, sscale, sshift, abuf);

        fused_mlp_kernel<<<NP / 128, 512, FUSED_LDS, stream>>>(
            abuf, W1T + (size_t)l * HD2 * HD, b1 + (size_t)l * HD2,
            W2T + (size_t)l * HD * HD2, b2 + (size_t)l * HD, zbuf, stats);

        bnprep_kernel<<<1, 256, 0, stream>>>(
            stats, gamma + (size_t)l * HD, beta + (size_t)l * HD, sscale, sshift, NN);
    }

    // ---- fused mean pool + head (BN on the fly) ----
    pool_head_kernel<<<NG, 256, 0, stream>>>(zbuf, batch, sscale, sshift,
                                             Wp1, bp1, Wp2, bp2, (float*)d_out);
}

// Round 3
// 735.455 us; speedup vs baseline: 1.2696x; 1.2696x over previous
//
#include <hip/hip_runtime.h>

#define NN 100000
#define NP 100096          // 782 * 128, padded row count
#define EE 300000
#define DIN 128
#define HD  256
#define HD2 512
#define NL  4
#define NG  512
#define BN_EPS 1e-5f

typedef __attribute__((ext_vector_type(8))) short s8v;      // bf16x8 frag (4 VGPRs)
typedef __attribute__((ext_vector_type(4))) float f4v;      // fp32x4 acc

typedef unsigned short ushort_t;

// float -> bf16, round-to-nearest-even
static __device__ inline ushort_t f2bf(float f) {
    unsigned u = __float_as_uint(f);
    unsigned r = (u + 0x7fffu + ((u >> 16) & 1u)) >> 16;
    return (ushort_t)r;
}
static __device__ inline float bf2f(ushort_t h) {
    return __uint_as_float(((unsigned)h) << 16);
}
// bf16 pair unpack from packed u32: low half needs shift, high half mask-only
static __device__ inline float blo(unsigned v) { return __uint_as_float(v << 16); }
static __device__ inline float bhi(unsigned v) { return __uint_as_float(v & 0xffff0000u); }

// async global->LDS, 16B per lane; LDS dest = uniform base + lane*16
#define GLOAD_LDS16(g, l) __builtin_amdgcn_global_load_lds( \
    (const __attribute__((address_space(1))) unsigned int*)(const void*)(g), \
    (__attribute__((address_space(3))) unsigned int*)(void*)(l), 16, 0, 0)

// s_waitcnt immediates: vmcnt[3:0] | expcnt(7)<<4 | lgkmcnt(15)<<8 | vmcnt[5:4]<<14
#define WAITCNT_VM8 0xF78
#define WAITCNT_VM4 0xF74
#define WAITCNT_VM0 0xF70

// ---------------------------------------------------------------------------
// bf16 MFMA GEMM (kept for GEMM0 / input projection only).
// Block tile 128x128, BK=32, 4 waves, 3-stage circular LDS pipeline.
// ---------------------------------------------------------------------------
__global__ __launch_bounds__(256) void gemm_bf16(
    const ushort_t* __restrict__ A, int lda,
    const ushort_t* __restrict__ BT, int ldb,
    const float* __restrict__ bias,
    ushort_t* __restrict__ C, int ldc,
    int K, int doRelu,
    int doStats, float* __restrict__ stats, int Mvalid)
{
    extern __shared__ char smem[];
    ushort_t* lds = (ushort_t*)smem;            // 3 stages x (A 8KB | B 8KB)
    ushort_t* Cs  = lds;                        // epilogue reuse (32 KB)
    float* ssum   = (float*)(smem + 49152);     // [4][128]
    float* ssq    = ssum + 512;

    const int tid  = threadIdx.x;
    const int w    = tid >> 6;
    const int L    = tid & 63;
    const int lm   = L & 15;
    const int q    = L >> 4;
    const int row0 = blockIdx.x * 128;
    const int col0 = blockIdx.y * 128;

    const ushort_t* gAbase = A  + (size_t)lm * lda;
    const ushort_t* gBbase = BT + (size_t)lm * ldb;

    f4v acc[2][8] = {};

    const int niter = K >> 5;

    #define STAGE(buf, k0) do {                                              \
        ushort_t* As_ = lds + (buf) * 8192;                                  \
        ushort_t* Bs_ = As_ + 4096;                                          \
        const int kk_ = (k0) + q * 8;                                        \
        _Pragma("unroll")                                                    \
        for (int i_ = 0; i_ < 2; ++i_) {                                     \
            const int tl_ = w * 2 + i_;                                      \
            GLOAD_LDS16(gAbase + (size_t)(row0 + tl_ * 16) * lda + kk_,      \
                        As_ + tl_ * 512);                                    \
            GLOAD_LDS16(gBbase + (size_t)(col0 + tl_ * 16) * ldb + kk_,      \
                        Bs_ + tl_ * 512);                                    \
        }                                                                    \
    } while (0)

    STAGE(0, 0);
    if (niter > 1) STAGE(1, 32);
    if (niter > 2) STAGE(2, 64);

    int cur = 0;
    for (int it = 0; it < niter; ++it) {
        const int rem = niter - 1 - it;
        if (rem >= 2)      __builtin_amdgcn_s_waitcnt(WAITCNT_VM8);
        else if (rem == 1) __builtin_amdgcn_s_waitcnt(WAITCNT_VM4);
        else               __builtin_amdgcn_s_waitcnt(WAITCNT_VM0);
        __builtin_amdgcn_s_barrier();

        const ushort_t* Ab = lds + cur * 8192;
        const ushort_t* Bb = Ab + 4096;
        s8v a0 = *(const s8v*)&Ab[(2 * w)     * 512 + L * 8];
        s8v a1 = *(const s8v*)&Ab[(2 * w + 1) * 512 + L * 8];
#pragma unroll
        for (int nt = 0; nt < 8; ++nt) {
            s8v b = *(const s8v*)&Bb[nt * 512 + L * 8];
            acc[0][nt] = __builtin_amdgcn_mfma_f32_16x16x32_bf16(a0, b, acc[0][nt], 0, 0, 0);
            acc[1][nt] = __builtin_amdgcn_mfma_f32_16x16x32_bf16(a1, b, acc[1][nt], 0, 0, 0);
        }
        __builtin_amdgcn_s_barrier();
        if (it + 3 < niter) STAGE(cur, (it + 3) * 32);
        cur = (cur == 2) ? 0 : cur + 1;
    }
    #undef STAGE

    __syncthreads();

    // epilogue: bias + relu + cvt; C/D frag: col = lm, row = q*4 + r
    float cs[8] = {};
    float cq[8] = {};
#pragma unroll
    for (int mt = 0; mt < 2; ++mt) {
#pragma unroll
        for (int nt = 0; nt < 8; ++nt) {
            const float bj = bias[col0 + nt * 16 + lm];
            f4v v = acc[mt][nt];
#pragma unroll
            for (int r = 0; r < 4; ++r) {
                float f = v[r] + bj;
                if (doRelu) f = fmaxf(f, 0.f);
                const int row = (2 * w + mt) * 16 + q * 4 + r;
                const int col = nt * 16 + lm;
                Cs[row * 128 + col] = f2bf(f);
                if (doStats && (row0 + row) < Mvalid) {
                    cs[nt] += f;
                    cq[nt] += f * f;
                }
            }
        }
    }
    if (doStats) {
#pragma unroll
        for (int nt = 0; nt < 8; ++nt) {
            float s = cs[nt], sq = cq[nt];
            s  += __shfl_xor(s, 16, 64);  s  += __shfl_xor(s, 32, 64);
            sq += __shfl_xor(sq, 16, 64); sq += __shfl_xor(sq, 32, 64);
            cs[nt] = s; cq[nt] = sq;
        }
    }
    __syncthreads();
    if (doStats && q == 0) {
#pragma unroll
        for (int nt = 0; nt < 8; ++nt) {
            ssum[w * 128 + nt * 16 + lm] = cs[nt];
            ssq [w * 128 + nt * 16 + lm] = cq[nt];
        }
    }
#pragma unroll
    for (int i = 0; i < 8; ++i) {
        const int idx = i * 256 + tid;
        const int row = idx >> 4, ch = idx & 15;
        s8v val = *(const s8v*)&Cs[row * 128 + ch * 8];
        *(s8v*)(C + (size_t)(row0 + row) * ldc + col0 + ch * 8) = val;
    }
    if (doStats) {
        __syncthreads();
        if (tid < 128) {
            const float s  = ssum[tid] + ssum[128 + tid] + ssum[256 + tid] + ssum[384 + tid];
            const float sq = ssq[tid]  + ssq[128 + tid]  + ssq[256 + tid]  + ssq[384 + tid];
            unsafeAtomicAdd(&stats[col0 + tid], s);
            unsafeAtomicAdd(&stats[HD + col0 + tid], sq);
        }
    }
}

// ---------------------------------------------------------------------------
// Weight packing into MFMA-fragment order so fused_mlp staging is contiguous
// 1KB bursts. Unit = 1KB = [lane L][e 0..7] bf16. Fragment is built directly
// in an ext_vector register (NO address-taken stack array -> no scratch
// misalignment hazard).
// W1 input [NL][HD][HD2] f32 (in x out). Unit (l, c, u): kk=u>>1, nt=u&1;
//   value = W1[l][kk*32 + (L>>4)*8 + e][c*32 + nt*16 + (L&15)].
__global__ __launch_bounds__(256) void pack_w1_kernel(
    const float* __restrict__ W1, ushort_t* __restrict__ W1P)
{
    const int t = threadIdx.x, L = t & 63;
    const int gu = blockIdx.x * 4 + (t >> 6);      // 0..1023
    const int l = gu >> 8, rem = gu & 255;
    const int c = rem >> 4, u = rem & 15;
    const int kk = u >> 1, nt = u & 1;
    const int h  = c * 32 + nt * 16 + (L & 15);
    const int k0 = kk * 32 + (L >> 4) * 8;
    const float* src = W1 + (size_t)l * HD * HD2;
    s8v v;
#pragma unroll
    for (int e = 0; e < 8; ++e)
        v[e] = (short)f2bf(src[(size_t)(k0 + e) * HD2 + h]);
    *(s8v*)(W1P + (size_t)gu * 512 + L * 8) = v;
}

// W2 input [NL][HD2][HD] f32. Unit (l, c, nt):
//   value = W2[l][c*32 + (L>>4)*8 + e][nt*16 + (L&15)].
__global__ __launch_bounds__(256) void pack_w2_kernel(
    const float* __restrict__ W2, ushort_t* __restrict__ W2P)
{
    const int t = threadIdx.x, L = t & 63;
    const int gu = blockIdx.x * 4 + (t >> 6);      // 0..1023
    const int l = gu >> 8, rem = gu & 255;
    const int c = rem >> 4, nt = rem & 15;
    const int h  = nt * 16 + (L & 15);
    const int k0 = c * 32 + (L >> 4) * 8;
    const float* src = W2 + (size_t)l * HD2 * HD;
    s8v v;
#pragma unroll
    for (int e = 0; e < 8; ++e)
        v[e] = (short)f2bf(src[(size_t)(k0 + e) * HD + h]);
    *(s8v*)(W2P + (size_t)gu * 512 + L * 8) = v;
}

// ---------------------------------------------------------------------------
// Fused GIN MLP v2: z = (agg @ W1 + b1).relu() @ W2 + b2, plus column stats.
//
// vs v1 (154 us, = unfused sum; latency-bound, 1 block/CU, vmcnt(0) drains):
//  - chunk = 32 hidden cols (16 chunks); W stage = 16KB W1c + 16KB W2c,
//    double-buffered = 64KB; hchunk 8 x 1.25KB; bias 2KB -> 80KB LDS TOTAL
//    => 2 blocks/CU, 16 waves (4/SIMD): blocks cover each other's drains
//    (m97's mechanism).
//  - counted vmcnt(4): one chunk always in flight, never drained mid-loop.
//    Biases pre-staged to LDS so no stray VMEM ops corrupt the count.
//  - weights pre-packed (pack_w*_kernel) so each global_load_lds is one
//    contiguous 1KB burst (v1: 16 scattered 64B segments per instr).
//  - s_setprio around MFMA clusters (T5; preconditions now exist).
// ---------------------------------------------------------------------------
__global__ __launch_bounds__(512, 4) void fused_mlp_kernel(
    const ushort_t* __restrict__ A,      // [NP, HD] bf16 (aggregate out)
    const ushort_t* __restrict__ W1l,    // [256 units x 512] packed bf16
    const float*    __restrict__ b1l,    // [HD2]
    const ushort_t* __restrict__ W2l,    // [256 units x 512] packed bf16
    const float*    __restrict__ b2l,    // [HD]
    ushort_t* __restrict__ C,            // [NP, HD] bf16 (pre-BN z)
    float* __restrict__ stats)           // [2*HD] col sum / sumsq (atomic)
{
    extern __shared__ char smem[];
    ushort_t* lds = (ushort_t*)smem;
    const int tid = threadIdx.x;
    const int w   = tid >> 6;            // wave 0..7 -> rows [w*16, w*16+16)
    const int L   = tid & 63;
    const int lm  = L & 15;
    const int q   = L >> 4;
    const int row0 = blockIdx.x * 128;

    // LDS map (bytes): 0..32767 buf0 | 32768..65535 buf1 |
    // 65536..75775 hchunk (8 x 1280) | 75776..77823 b1s | rest spare.
    // Epilogue overlay: Cs 0..65535 | ssum 65536..73727 | ssq 73728..81919.
    float* b1s = (float*)(smem + 75776);
    char*  hcb = smem + 65536 + w * 1280;   // wave-private [16 rows][80B]

    // ---- biases -> LDS (consumed before the syncthreads drains vmcnt) ----
    if (tid < HD2) b1s[tid] = b1l[tid];
    __syncthreads();

    // ---- A slice in registers: a[kk] = A-frag for k-step kk (K=256) ----
    const ushort_t* Arow = A + (size_t)(row0 + w * 16 + lm) * HD;
    s8v a[8];
#pragma unroll
    for (int kk = 0; kk < 8; ++kk)
        a[kk] = *(const s8v*)(Arow + kk * 32 + q * 8);
    __builtin_amdgcn_s_waitcnt(WAITCNT_VM0);   // a[] resident; vmcnt clean

    // stage chunk cc into buf: 32 contiguous 1KB units, 4 per wave.
    // buf layout (ushorts): W1c at +0 (16 units), W2c at +8192 (16 units).
#define STAGE_W(buf, cc) do {                                                 \
    ushort_t* Wb_ = lds + (buf) * 16384;                                      \
    if (w < 4) {                                                              \
        _Pragma("unroll")                                                     \
        for (int i_ = 0; i_ < 4; ++i_) {                                      \
            const int u_ = w * 4 + i_;                                        \
            GLOAD_LDS16(W1l + ((cc) * 16 + u_) * 512 + L * 8,                 \
                        Wb_ + u_ * 512);                                      \
        }                                                                     \
    } else {                                                                  \
        _Pragma("unroll")                                                     \
        for (int i_ = 0; i_ < 4; ++i_) {                                      \
            const int u_ = (w - 4) * 4 + i_;                                  \
            GLOAD_LDS16(W2l + ((cc) * 16 + u_) * 512 + L * 8,                 \
                        Wb_ + 8192 + u_ * 512);                               \
        }                                                                     \
    }                                                                         \
} while (0)

    STAGE_W(0, 0);
    STAGE_W(1, 1);

    f4v acc2[16] = {};                   // z rows w*16.. x 256 cols
    for (int c = 0; c < 16; ++c) {
        // counted wait: stage(c) landed, stage(c+1)'s 4 loads stay in flight
        if (c < 15) __builtin_amdgcn_s_waitcnt(WAITCNT_VM4);
        else        __builtin_amdgcn_s_waitcnt(WAITCNT_VM0);
        __builtin_amdgcn_s_barrier();
        __builtin_amdgcn_sched_barrier(0);

        const ushort_t* Wb  = lds + (c & 1) * 16384;
        const ushort_t* W2b = Wb + 8192;

        // GEMM1: hchunk = A x W1c  (2 chains x 8 deep)
        f4v acc1[2] = {};
        __builtin_amdgcn_s_setprio(1);
#pragma unroll
        for (int kk = 0; kk < 8; ++kk) {
#pragma unroll
            for (int nt = 0; nt < 2; ++nt) {
                s8v b = *(const s8v*)&Wb[(kk * 2 + nt) * 512 + L * 8];
                acc1[nt] = __builtin_amdgcn_mfma_f32_16x16x32_bf16(a[kk], b, acc1[nt], 0, 0, 0);
            }
        }
        __builtin_amdgcn_s_setprio(0);

        // bias + relu + bf16 -> wave-private LDS [16][80B] (frag transpose)
#pragma unroll
        for (int nt = 0; nt < 2; ++nt) {
            const float bj = b1s[c * 32 + nt * 16 + lm];
#pragma unroll
            for (int r = 0; r < 4; ++r) {
                const int rr = q * 4 + r;
                *(ushort_t*)(hcb + rr * 80 + (nt * 16 + lm) * 2) =
                    f2bf(fmaxf(acc1[nt][r] + bj, 0.f));
            }
        }
        // GEMM2: zacc += hchunk x W2c  (16 independent 1-deep chains)
        const s8v at = *(const s8v*)(hcb + lm * 80 + q * 16);
        __builtin_amdgcn_s_setprio(1);
#pragma unroll
        for (int nt = 0; nt < 16; ++nt) {
            s8v b = *(const s8v*)&W2b[nt * 512 + L * 8];
            acc2[nt] = __builtin_amdgcn_mfma_f32_16x16x32_bf16(at, b, acc2[nt], 0, 0, 0);
        }
        __builtin_amdgcn_s_setprio(0);

        __builtin_amdgcn_sched_barrier(0);
        __builtin_amdgcn_s_barrier();
        if (c + 2 < 16) STAGE_W((c & 1), c + 2);
    }
#undef STAGE_W

    __syncthreads();

    // ---- epilogue: bias + stats + bf16, LDS bounce for coalesced store ----
    ushort_t* Cs = lds;                      // [128][256] bf16, 64KB
    float* ssum  = (float*)(smem + 65536);   // [8][256]
    float* ssq   = (float*)(smem + 73728);   // [8][256]

#pragma unroll
    for (int nt = 0; nt < 16; ++nt) {
        const float bj = b2l[nt * 16 + lm];
        float s = 0.f, sq = 0.f;
#pragma unroll
        for (int r = 0; r < 4; ++r) {
            const float f  = acc2[nt][r] + bj;
            const int row  = w * 16 + q * 4 + r;
            Cs[row * 256 + nt * 16 + lm] = f2bf(f);
            if (row0 + row < NN) { s += f; sq += f * f; }
        }
        s  += __shfl_xor(s, 16, 64);  s  += __shfl_xor(s, 32, 64);
        sq += __shfl_xor(sq, 16, 64); sq += __shfl_xor(sq, 32, 64);
        if (q == 0) {
            ssum[w * 256 + nt * 16 + lm] = s;
            ssq [w * 256 + nt * 16 + lm] = sq;
        }
    }
    __syncthreads();

#pragma unroll
    for (int i = 0; i < 8; ++i) {
        const int idx = i * 512 + tid;       // 16B unit among 4096
        const int row = idx >> 5, ch = idx & 31;
        const s8v v = *(const s8v*)&Cs[idx * 8];
        *(s8v*)(C + (size_t)(row0 + row) * HD + ch * 8) = v;
    }
    if (tid < HD) {
        float s = 0.f, sq = 0.f;
#pragma unroll
        for (int ww = 0; ww < 8; ++ww) {
            s  += ssum[ww * 256 + tid];
            sq += ssq [ww * 256 + tid];
        }
        unsafeAtomicAdd(&stats[tid], s);
        unsafeAtomicAdd(&stats[HD + tid], sq);
    }
}

// ---------------------------------------------------------------------------
// Batched transpose + fp32->bf16: out[z][c][r] = in[z][r][c]; blockIdx.z = batch.
__global__ __launch_bounds__(256) void transpose_cvt_kernel(
    const float* __restrict__ in, ushort_t* __restrict__ out, int R, int C,
    long inStride, long outStride)
{
    __shared__ float tile[32][33];
    const float* inp  = in  + (size_t)blockIdx.z * inStride;
    ushort_t*    outp = out + (size_t)blockIdx.z * outStride;
    const int bx = blockIdx.x * 32;
    const int by = blockIdx.y * 32;
    const int tx = threadIdx.x & 31;
    const int ty = threadIdx.x >> 5;
#pragma unroll
    for (int i = 0; i < 32; i += 8)
        tile[ty + i][tx] = inp[(size_t)(by + ty + i) * C + bx + tx];
    __syncthreads();
#pragma unroll
    for (int i = 0; i < 32; i += 8)
        outp[(size_t)(bx + ty + i) * R + by + tx] = f2bf(tile[tx][ty + i]);
}

__global__ __launch_bounds__(256) void cvt_kernel(
    const float* __restrict__ in, ushort_t* __restrict__ out, long n4)
{
    const long i = (long)blockIdx.x * 256 + threadIdx.x;
    if (i >= n4) return;
    const float4 v = ((const float4*)in)[i];
    ushort4 o;
    o.x = f2bf(v.x); o.y = f2bf(v.y); o.z = f2bf(v.z); o.w = f2bf(v.w);
    ((ushort4*)out)[i] = o;
}

__global__ __launch_bounds__(256) void zero_kernel(float* __restrict__ p, long n4)
{
    const long i = (long)blockIdx.x * 256 + threadIdx.x;
    if (i < n4) ((float4*)p)[i] = make_float4(0.f, 0.f, 0.f, 0.f);
}

// identity scale/shift + zeroed stats (once per call, before layer 0)
__global__ __launch_bounds__(256) void init_bn_kernel(
    float* __restrict__ sscale, float* __restrict__ sshift,
    float* __restrict__ stats)
{
    const int t = threadIdx.x;
    sscale[t] = 1.f;
    sshift[t] = 0.f;
    stats[t] = 0.f;
    stats[HD + t] = 0.f;
}

// scale/shift from stats; re-zero stats for the next layer
__global__ __launch_bounds__(256) void bnprep_kernel(
    float* __restrict__ stats, const float* __restrict__ gamma,
    const float* __restrict__ beta, float* __restrict__ sscale,
    float* __restrict__ sshift, int Nn)
{
    const int t = threadIdx.x;
    const float invN = 1.0f / (float)Nn;
    const float mu  = stats[t] * invN;
    const float var = stats[HD + t] * invN - mu * mu;
    const float inv = rsqrtf(var + BN_EPS);
    const float sc  = gamma[t] * inv;
    sscale[t] = sc;
    sshift[t] = beta[t] - mu * sc;
    stats[t] = 0.f;
    stats[HD + t] = 0.f;
}

// ---------------- CSR build (per call; edges are layer-invariant) -----------
__global__ __launch_bounds__(256) void hist_kernel(
    const int* __restrict__ dst, int* __restrict__ deg, int E)
{
    const int e = blockIdx.x * 256 + threadIdx.x;
    if (e < E) atomicAdd(&deg[dst[e]], 1);
}

__global__ __launch_bounds__(256) void scan1_kernel(
    const int* __restrict__ deg, int* __restrict__ partial,
    int* __restrict__ bsums, int n)
{
    __shared__ int tmp[256];
    const int i = blockIdx.x * 256 + threadIdx.x;
    const int v = (i < n) ? deg[i] : 0;
    tmp[threadIdx.x] = v;
    __syncthreads();
    for (int off = 1; off < 256; off <<= 1) {
        const int t = (threadIdx.x >= off) ? tmp[threadIdx.x - off] : 0;
        __syncthreads();
        tmp[threadIdx.x] += t;
        __syncthreads();
    }
    if (i < n) partial[i] = tmp[threadIdx.x] - v;
    if (threadIdx.x == 255) bsums[blockIdx.x] = tmp[255];
}

__global__ __launch_bounds__(512) void scan2_kernel(int* __restrict__ bsums, int nb)
{
    __shared__ int tmp[512];
    const int i = threadIdx.x;
    const int v = (i < nb) ? bsums[i] : 0;
    tmp[i] = v;
    __syncthreads();
    for (int off = 1; off < 512; off <<= 1) {
        const int t = (i >= off) ? tmp[i - off] : 0;
        __syncthreads();
        tmp[i] += t;
        __syncthreads();
    }
    if (i < nb) bsums[i] = tmp[i] - v;
}

__global__ __launch_bounds__(256) void scan3_kernel(
    const int* __restrict__ partial, const int* __restrict__ bsums,
    int* __restrict__ offs, int* __restrict__ cursor, int n)
{
    const int i = blockIdx.x * 256 + threadIdx.x;
    if (i < n) {
        const int o = partial[i] + bsums[blockIdx.x];
        offs[i] = o;
        cursor[i] = o;
    }
}

__global__ __launch_bounds__(256) void scatter_kernel(
    const int* __restrict__ src, const int* __restrict__ dst,
    int* __restrict__ cursor, int* __restrict__ srcSorted, int E)
{
    const int e = blockIdx.x * 256 + threadIdx.x;
    if (e >= E) return;
    const int p = atomicAdd(&cursor[dst[e]], 1);
    srcSorted[p] = src[e];
}

// ---------------------------------------------------------------------------
// out[n] = bf16( (1+eps)*y[n] + sum_{s in nbrs(n)} y[s] ),
// y[i] = relu( z[i]*sscale + sshift )  (BN on the fly).
__global__ __launch_bounds__(256) void aggregate_kernel(
    const ushort_t* __restrict__ z, const int* __restrict__ offs,
    const int* __restrict__ deg, const int* __restrict__ srcSorted,
    const float* __restrict__ epsArr, int epsIdx,
    const float* __restrict__ sscale, const float* __restrict__ sshift,
    ushort_t* __restrict__ out)
{
    const int n = blockIdx.x * 8 + (threadIdx.x >> 5);   // 8 nodes / 256 thr
    const int L = threadIdx.x & 31;
    const int c0 = L * 8;
    const float4 scA = *(const float4*)(sscale + c0);
    const float4 scB = *(const float4*)(sscale + c0 + 4);
    const float4 shA = *(const float4*)(sshift + c0);
    const float4 shB = *(const float4*)(sshift + c0 + 4);
    const int start = offs[n];
    const int dc = deg[n];
    float a[8] = {};
    float b[8] = {};
    int j = 0;
    for (; j + 1 < dc; j += 2) {
        const int s0 = srcSorted[start + j];
        const int s1 = srcSorted[start + j + 1];
        const uint4 u = *(const uint4*)(z + (size_t)s0 * HD + c0);
        const uint4 v = *(const uint4*)(z + (size_t)s1 * HD + c0);
        a[0] += fmaxf(blo(u.x) * scA.x + shA.x, 0.f);
        a[1] += fmaxf(bhi(u.x) * scA.y + shA.y, 0.f);
        a[2] += fmaxf(blo(u.y) * scA.z + shA.z, 0.f);
        a[3] += fmaxf(bhi(u.y) * scA.w + shA.w, 0.f);
        a[4] += fmaxf(blo(u.z) * scB.x + shB.x, 0.f);
        a[5] += fmaxf(bhi(u.z) * scB.y + shB.y, 0.f);
        a[6] += fmaxf(blo(u.w) * scB.z + shB.z, 0.f);
        a[7] += fmaxf(bhi(u.w) * scB.w + shB.w, 0.f);
        b[0] += fmaxf(blo(v.x) * scA.x + shA.x, 0.f);
        b[1] += fmaxf(bhi(v.x) * scA.y + shA.y, 0.f);
        b[2] += fmaxf(blo(v.y) * scA.z + shA.z, 0.f);
        b[3] += fmaxf(bhi(v.y) * scA.w + shA.w, 0.f);
        b[4] += fmaxf(blo(v.z) * scB.x + shB.x, 0.f);
        b[5] += fmaxf(bhi(v.z) * scB.y + shB.y, 0.f);
        b[6] += fmaxf(blo(v.w) * scB.z + shB.z, 0.f);
        b[7] += fmaxf(bhi(v.w) * scB.w + shB.w, 0.f);
    }
    if (j < dc) {
        const int s0 = srcSorted[start + j];
        const uint4 u = *(const uint4*)(z + (size_t)s0 * HD + c0);
        a[0] += fmaxf(blo(u.x) * scA.x + shA.x, 0.f);
        a[1] += fmaxf(bhi(u.x) * scA.y + shA.y, 0.f);
        a[2] += fmaxf(blo(u.y) * scA.z + shA.z, 0.f);
        a[3] += fmaxf(bhi(u.y) * scA.w + shA.w, 0.f);
        a[4] += fmaxf(blo(u.z) * scB.x + shB.x, 0.f);
        a[5] += fmaxf(bhi(u.z) * scB.y + shB.y, 0.f);
        a[6] += fmaxf(blo(u.w) * scB.z + shB.z, 0.f);
        a[7] += fmaxf(bhi(u.w) * scB.w + shB.w, 0.f);
    }
#pragma unroll
    for (int k = 0; k < 8; ++k) a[k] += b[k];
    const float se = 1.0f + epsArr[epsIdx];
    const uint4 hs = *(const uint4*)(z + (size_t)n * HD + c0);
    float y[8];
    y[0] = se * fmaxf(blo(hs.x) * scA.x + shA.x, 0.f) + a[0];
    y[1] = se * fmaxf(bhi(hs.x) * scA.y + shA.y, 0.f) + a[1];
    y[2] = se * fmaxf(blo(hs.y) * scA.z + shA.z, 0.f) + a[2];
    y[3] = se * fmaxf(bhi(hs.y) * scA.w + shA.w, 0.f) + a[3];
    y[4] = se * fmaxf(blo(hs.z) * scB.x + shB.x, 0.f) + a[4];
    y[5] = se * fmaxf(bhi(hs.z) * scB.y + shB.y, 0.f) + a[5];
    y[6] = se * fmaxf(blo(hs.w) * scB.z + shB.z, 0.f) + a[6];
    y[7] = se * fmaxf(bhi(hs.w) * scB.w + shB.w, 0.f) + a[7];
    uint4 o;
    o.x = (unsigned)f2bf(y[0]) | ((unsigned)f2bf(y[1]) << 16);
    o.y = (unsigned)f2bf(y[2]) | ((unsigned)f2bf(y[3]) << 16);
    o.z = (unsigned)f2bf(y[4]) | ((unsigned)f2bf(y[5]) << 16);
    o.w = (unsigned)f2bf(y[6]) | ((unsigned)f2bf(y[7]) << 16);
    *(uint4*)(out + (size_t)n * HD + c0) = o;
}

// ---------------------------------------------------------------------------
// Fused mean-pool + head, BN on the fly.
__global__ __launch_bounds__(256) void pool_head_kernel(
    const ushort_t* __restrict__ z, const int* __restrict__ batch,
    const float* __restrict__ sscale, const float* __restrict__ sshift,
    const float* __restrict__ Wp1, const float* __restrict__ bp1,
    const float* __restrict__ Wp2, const float* __restrict__ bp2,
    float* __restrict__ out)
{
    __shared__ float poolw[4][HD];
    __shared__ float pool[HD];
    __shared__ float red[128];
    __shared__ int seg[2];
    const int g = blockIdx.x;
    const int t = threadIdx.x;
    const int w = t >> 6;
    const int L = t & 63;
    if (t == 0) {
        int lo = 0, hi = NN;
        while (lo < hi) { const int m = (lo + hi) >> 1; if (batch[m] < g) lo = m + 1; else hi = m; }
        seg[0] = lo;
        hi = NN;
        while (lo < hi) { const int m = (lo + hi) >> 1; if (batch[m] < g + 1) lo = m + 1; else hi = m; }
        seg[1] = lo;
    }
    __syncthreads();
    const int start = seg[0], end = seg[1];
    const int c0 = L * 4;
    const float4 sc = *(const float4*)(sscale + c0);
    const float4 sh = *(const float4*)(sshift + c0);
    float a0 = 0.f, a1 = 0.f, a2 = 0.f, a3 = 0.f;
    float b0 = 0.f, b1 = 0.f, b2 = 0.f, b3 = 0.f;
    int r = start + w;
    for (; r + 4 < end; r += 8) {
        const ushort4 u = *(const ushort4*)(z + (size_t)r * HD + c0);
        const ushort4 v = *(const ushort4*)(z + (size_t)(r + 4) * HD + c0);
        a0 += fmaxf(bf2f(u.x) * sc.x + sh.x, 0.f);
        a1 += fmaxf(bf2f(u.y) * sc.y + sh.y, 0.f);
        a2 += fmaxf(bf2f(u.z) * sc.z + sh.z, 0.f);
        a3 += fmaxf(bf2f(u.w) * sc.w + sh.w, 0.f);
        b0 += fmaxf(bf2f(v.x) * sc.x + sh.x, 0.f);
        b1 += fmaxf(bf2f(v.y) * sc.y + sh.y, 0.f);
        b2 += fmaxf(bf2f(v.z) * sc.z + sh.z, 0.f);
        b3 += fmaxf(bf2f(v.w) * sc.w + sh.w, 0.f);
    }
    if (r < end) {
        const ushort4 u = *(const ushort4*)(z + (size_t)r * HD + c0);
        a0 += fmaxf(bf2f(u.x) * sc.x + sh.x, 0.f);
        a1 += fmaxf(bf2f(u.y) * sc.y + sh.y, 0.f);
        a2 += fmaxf(bf2f(u.z) * sc.z + sh.z, 0.f);
        a3 += fmaxf(bf2f(u.w) * sc.w + sh.w, 0.f);
    }
    poolw[w][c0 + 0] = a0 + b0;
    poolw[w][c0 + 1] = a1 + b1;
    poolw[w][c0 + 2] = a2 + b2;
    poolw[w][c0 + 3] = a3 + b3;
    __syncthreads();
    const float invC = 1.0f / (float)max(end - start, 1);
    pool[t] = (poolw[0][t] + poolw[1][t] + poolw[2][t] + poolw[3][t]) * invC;
    __syncthreads();
    if (t < 128) {
        float acc = 0.f;
#pragma unroll 4
        for (int k = 0; k < HD; ++k)
            acc += pool[k] * Wp1[k * 128 + t];
        red[t] = fmaxf(acc + bp1[t], 0.f) * Wp2[t];
    }
    __syncthreads();
    for (int sft = 64; sft > 0; sft >>= 1) {
        if (t < sft) red[t] += red[t + sft];
        __syncthreads();
    }
    if (t == 0) out[g] = red[0] + bp2[0];
}

// ---------------------------------------------------------------------------
extern "C" void kernel_launch(void* const* d_in, const int* in_sizes, int n_in,
                              void* d_out, int out_size, void* d_ws, size_t ws_size,
                              hipStream_t stream)
{
    const float* x     = (const float*)d_in[0];
    const int*   ei    = (const int*)  d_in[1];
    const int*   batch = (const int*)  d_in[2];
    const float* W_in  = (const float*)d_in[3];
    const float* b_in  = (const float*)d_in[4];
    const float* eps   = (const float*)d_in[5];
    const float* W1    = (const float*)d_in[6];
    const float* b1    = (const float*)d_in[7];
    const float* W2    = (const float*)d_in[8];
    const float* b2    = (const float*)d_in[9];
    const float* gamma = (const float*)d_in[10];
    const float* beta  = (const float*)d_in[11];
    const float* Wp1   = (const float*)d_in[12];
    const float* bp1   = (const float*)d_in[13];
    const float* Wp2   = (const float*)d_in[14];
    const float* bp2   = (const float*)d_in[15];

    const int* srcIdx = ei;
    const int* dstIdx = ei + EE;

    // ---- workspace layout ----
    char* p = (char*)d_ws;
    ushort_t* zbuf    = (ushort_t*)p;  p += (size_t)NP * HD  * 2;   // pre-BN acts
    ushort_t* abuf    = (ushort_t*)p;  p += (size_t)NP * HD  * 2;   // aggregate out
    ushort_t* hidden  = (ushort_t*)p;  p += (size_t)NP * HD2 * 2;   // x_bf alias (GEMM0 A)
    ushort_t* W1P     = (ushort_t*)p;  p += (size_t)NL * HD2 * HD * 2;   // packed
    ushort_t* W2P     = (ushort_t*)p;  p += (size_t)NL * HD * HD2 * 2;   // packed
    ushort_t* WinT    = (ushort_t*)p;  p += (size_t)HD * DIN * 2;
    int* deg          = (int*)p;       p += (size_t)NN * 4;
    int* partial      = (int*)p;       p += (size_t)NN * 4;
    int* bsums        = (int*)p;       p += 512 * 4;
    int* offs         = (int*)p;       p += (size_t)NN * 4;
    int* cursor       = (int*)p;       p += (size_t)NN * 4;
    int* srcSorted    = (int*)p;       p += (size_t)EE * 4;
    float* stats      = (float*)p;     p += 2 * HD * 4;
    float* sscale     = (float*)p;     p += HD * 4;
    float* sshift     = (float*)p;     p += HD * 4;
    ushort_t* x_bf    = hidden;        // GEMM0 A

    const int nb = (NN + 255) / 256;   // 391
    const int GEMM_LDS  = 53248;       // gemm_bf16: 3 x 16KB stages + 4KB stats
    const int FUSED_LDS = 81920;       // fused_mlp v2: 2x32KB W + hchunk + bias

    // ---- BN identity + stats zero ----
    init_bn_kernel<<<1, 256, 0, stream>>>(sscale, sshift, stats);

    // ---- weight conversion (Win transposed bf16; W1/W2 packed frag-order) --
    transpose_cvt_kernel<<<dim3(HD / 32, DIN / 32, 1), 256, 0, stream>>>(
        W_in, WinT, DIN, HD, 0, 0);
    pack_w1_kernel<<<256, 256, 0, stream>>>(W1, W1P);
    pack_w2_kernel<<<256, 256, 0, stream>>>(W2, W2P);
    cvt_kernel<<<(int)(((long)NN * DIN / 4 + 255) / 256), 256, 0, stream>>>(
        x, x_bf, (long)NN * DIN / 4);

    // ---- CSR build (once; edges layer-invariant) ----
    zero_kernel<<<(NN / 4 + 255) / 256, 256, 0, stream>>>((float*)deg, NN / 4);
    hist_kernel<<<(EE + 255) / 256, 256, 0, stream>>>(dstIdx, deg, EE);
    scan1_kernel<<<nb, 256, 0, stream>>>(deg, partial, bsums, NN);
    scan2_kernel<<<1, 512, 0, stream>>>(bsums, nb);
    scan3_kernel<<<nb, 256, 0, stream>>>(partial, bsums, offs, cursor, NN);
    scatter_kernel<<<(EE + 255) / 256, 256, 0, stream>>>(srcIdx, dstIdx, cursor, srcSorted, EE);

    // ---- input projection: zbuf = relu(x @ W_in + b_in)  (identity BN) ----
    gemm_bf16<<<dim3(NP / 128, HD / 128), 256, GEMM_LDS, stream>>>(
        x_bf, DIN, WinT, DIN, b_in, zbuf, HD, DIN, 1, 0, nullptr, 0);

    // ---- GIN layers: aggregate -> fused MLP (+stats) -> BN prep ----
    for (int l = 0; l < NL; ++l) {
        aggregate_kernel<<<NN / 8, 256, 0, stream>>>(
            zbuf, offs, deg, srcSorted, eps, l, sscale, sshift, abuf);

        fused_mlp_kernel<<<NP / 128, 512, FUSED_LDS, stream>>>(
            abuf, W1P + (size_t)l * HD2 * HD, b1 + (size_t)l * HD2,
            W2P + (size_t)l * HD * HD2, b2 + (size_t)l * HD, zbuf, stats);

        bnprep_kernel<<<1, 256, 0, stream>>>(
            stats, gamma + (size_t)l * HD, beta + (size_t)l * HD, sscale, sshift, NN);
    }

    // ---- fused mean pool + head (BN on the fly) ----
    pool_head_kernel<<<NG, 256, 0, stream>>>(zbuf, batch, sscale, sshift,
                                             Wp1, bp1, Wp2, bp2, (float*)d_out);
}

// Round 4
// 734.211 us; speedup vs baseline: 1.2718x; 1.0017x over previous
//
#include <hip/hip_runtime.h>

#define NN 100000
#define NP 100096          // 782 * 128, padded row count
#define EE 300000
#define DIN 128
#define HD  256
#define HD2 512
#define NL  4
#define NG  512
#define BN_EPS 1e-5f

typedef __attribute__((ext_vector_type(8))) short s8v;      // bf16x8 frag (4 VGPRs)
typedef __attribute__((ext_vector_type(4))) float f4v;      // fp32x4 acc

typedef unsigned short ushort_t;

// float -> bf16, round-to-nearest-even
static __device__ inline ushort_t f2bf(float f) {
    unsigned u = __float_as_uint(f);
    unsigned r = (u + 0x7fffu + ((u >> 16) & 1u)) >> 16;
    return (ushort_t)r;
}
static __device__ inline float bf2f(ushort_t h) {
    return __uint_as_float(((unsigned)h) << 16);
}
// bf16 pair unpack from packed u32: low half needs shift, high half mask-only
static __device__ inline float blo(unsigned v) { return __uint_as_float(v << 16); }
static __device__ inline float bhi(unsigned v) { return __uint_as_float(v & 0xffff0000u); }

// async global->LDS, 16B per lane; LDS dest = uniform base + lane*16
#define GLOAD_LDS16(g, l) __builtin_amdgcn_global_load_lds( \
    (const __attribute__((address_space(1))) unsigned int*)(const void*)(g), \
    (__attribute__((address_space(3))) unsigned int*)(void*)(l), 16, 0, 0)

// s_waitcnt immediates: vmcnt[3:0] | expcnt(7)<<4 | lgkmcnt(15)<<8 | vmcnt[5:4]<<14
#define WAITCNT_VM8 0xF78
#define WAITCNT_VM4 0xF74
#define WAITCNT_VM0 0xF70

// ---------------------------------------------------------------------------
// bf16 MFMA GEMM (kept for GEMM0 / input projection only).
// Block tile 128x128, BK=32, 4 waves, 3-stage circular LDS pipeline.
// ---------------------------------------------------------------------------
__global__ __launch_bounds__(256) void gemm_bf16(
    const ushort_t* __restrict__ A, int lda,
    const ushort_t* __restrict__ BT, int ldb,
    const float* __restrict__ bias,
    ushort_t* __restrict__ C, int ldc,
    int K, int doRelu,
    int doStats, float* __restrict__ stats, int Mvalid)
{
    extern __shared__ char smem[];
    ushort_t* lds = (ushort_t*)smem;            // 3 stages x (A 8KB | B 8KB)
    ushort_t* Cs  = lds;                        // epilogue reuse (32 KB)
    float* ssum   = (float*)(smem + 49152);     // [4][128]
    float* ssq    = ssum + 512;

    const int tid  = threadIdx.x;
    const int w    = tid >> 6;
    const int L    = tid & 63;
    const int lm   = L & 15;
    const int q    = L >> 4;
    const int row0 = blockIdx.x * 128;
    const int col0 = blockIdx.y * 128;

    const ushort_t* gAbase = A  + (size_t)lm * lda;
    const ushort_t* gBbase = BT + (size_t)lm * ldb;

    f4v acc[2][8] = {};

    const int niter = K >> 5;

    #define STAGE(buf, k0) do {                                              \
        ushort_t* As_ = lds + (buf) * 8192;                                  \
        ushort_t* Bs_ = As_ + 4096;                                          \
        const int kk_ = (k0) + q * 8;                                        \
        _Pragma("unroll")                                                    \
        for (int i_ = 0; i_ < 2; ++i_) {                                     \
            const int tl_ = w * 2 + i_;                                      \
            GLOAD_LDS16(gAbase + (size_t)(row0 + tl_ * 16) * lda + kk_,      \
                        As_ + tl_ * 512);                                    \
            GLOAD_LDS16(gBbase + (size_t)(col0 + tl_ * 16) * ldb + kk_,      \
                        Bs_ + tl_ * 512);                                    \
        }                                                                    \
    } while (0)

    STAGE(0, 0);
    if (niter > 1) STAGE(1, 32);
    if (niter > 2) STAGE(2, 64);

    int cur = 0;
    for (int it = 0; it < niter; ++it) {
        const int rem = niter - 1 - it;
        if (rem >= 2)      __builtin_amdgcn_s_waitcnt(WAITCNT_VM8);
        else if (rem == 1) __builtin_amdgcn_s_waitcnt(WAITCNT_VM4);
        else               __builtin_amdgcn_s_waitcnt(WAITCNT_VM0);
        __builtin_amdgcn_s_barrier();

        const ushort_t* Ab = lds + cur * 8192;
        const ushort_t* Bb = Ab + 4096;
        s8v a0 = *(const s8v*)&Ab[(2 * w)     * 512 + L * 8];
        s8v a1 = *(const s8v*)&Ab[(2 * w + 1) * 512 + L * 8];
#pragma unroll
        for (int nt = 0; nt < 8; ++nt) {
            s8v b = *(const s8v*)&Bb[nt * 512 + L * 8];
            acc[0][nt] = __builtin_amdgcn_mfma_f32_16x16x32_bf16(a0, b, acc[0][nt], 0, 0, 0);
            acc[1][nt] = __builtin_amdgcn_mfma_f32_16x16x32_bf16(a1, b, acc[1][nt], 0, 0, 0);
        }
        __builtin_amdgcn_s_barrier();
        if (it + 3 < niter) STAGE(cur, (it + 3) * 32);
        cur = (cur == 2) ? 0 : cur + 1;
    }
    #undef STAGE

    __syncthreads();

    // epilogue: bias + relu + cvt; C/D frag: col = lm, row = q*4 + r
    float cs[8] = {};
    float cq[8] = {};
#pragma unroll
    for (int mt = 0; mt < 2; ++mt) {
#pragma unroll
        for (int nt = 0; nt < 8; ++nt) {
            const float bj = bias[col0 + nt * 16 + lm];
            f4v v = acc[mt][nt];
#pragma unroll
            for (int r = 0; r < 4; ++r) {
                float f = v[r] + bj;
                if (doRelu) f = fmaxf(f, 0.f);
                const int row = (2 * w + mt) * 16 + q * 4 + r;
                const int col = nt * 16 + lm;
                Cs[row * 128 + col] = f2bf(f);
                if (doStats && (row0 + row) < Mvalid) {
                    cs[nt] += f;
                    cq[nt] += f * f;
                }
            }
        }
    }
    if (doStats) {
#pragma unroll
        for (int nt = 0; nt < 8; ++nt) {
            float s = cs[nt], sq = cq[nt];
            s  += __shfl_xor(s, 16, 64);  s  += __shfl_xor(s, 32, 64);
            sq += __shfl_xor(sq, 16, 64); sq += __shfl_xor(sq, 32, 64);
            cs[nt] = s; cq[nt] = sq;
        }
    }
    __syncthreads();
    if (doStats && q == 0) {
#pragma unroll
        for (int nt = 0; nt < 8; ++nt) {
            ssum[w * 128 + nt * 16 + lm] = cs[nt];
            ssq [w * 128 + nt * 16 + lm] = cq[nt];
        }
    }
#pragma unroll
    for (int i = 0; i < 8; ++i) {
        const int idx = i * 256 + tid;
        const int row = idx >> 4, ch = idx & 15;
        s8v val = *(const s8v*)&Cs[row * 128 + ch * 8];
        *(s8v*)(C + (size_t)(row0 + row) * ldc + col0 + ch * 8) = val;
    }
    if (doStats) {
        __syncthreads();
        if (tid < 128) {
            const float s  = ssum[tid] + ssum[128 + tid] + ssum[256 + tid] + ssum[384 + tid];
            const float sq = ssq[tid]  + ssq[128 + tid]  + ssq[256 + tid]  + ssq[384 + tid];
            unsafeAtomicAdd(&stats[col0 + tid], s);
            unsafeAtomicAdd(&stats[HD + col0 + tid], sq);
        }
    }
}

// ---------------------------------------------------------------------------
// Weight packing into MFMA-fragment order so fused_mlp staging is contiguous
// 1KB bursts. Unit = 1KB = [lane L][e 0..7] bf16. Fragment built directly in
// an ext_vector register (no address-taken stack array).
// W1 input [NL][HD][HD2] f32 (in x out). Unit (l, c, u): kk=u>>1, nt=u&1;
//   value = W1[l][kk*32 + (L>>4)*8 + e][c*32 + nt*16 + (L&15)].
__global__ __launch_bounds__(256) void pack_w1_kernel(
    const float* __restrict__ W1, ushort_t* __restrict__ W1P)
{
    const int t = threadIdx.x, L = t & 63;
    const int gu = blockIdx.x * 4 + (t >> 6);      // 0..1023
    const int l = gu >> 8, rem = gu & 255;
    const int c = rem >> 4, u = rem & 15;
    const int kk = u >> 1, nt = u & 1;
    const int h  = c * 32 + nt * 16 + (L & 15);
    const int k0 = kk * 32 + (L >> 4) * 8;
    const float* src = W1 + (size_t)l * HD * HD2;
    s8v v;
#pragma unroll
    for (int e = 0; e < 8; ++e)
        v[e] = (short)f2bf(src[(size_t)(k0 + e) * HD2 + h]);
    *(s8v*)(W1P + (size_t)gu * 512 + L * 8) = v;
}

// W2 input [NL][HD2][HD] f32. Unit (l, c, nt):
//   value = W2[l][c*32 + (L>>4)*8 + e][nt*16 + (L&15)].
__global__ __launch_bounds__(256) void pack_w2_kernel(
    const float* __restrict__ W2, ushort_t* __restrict__ W2P)
{
    const int t = threadIdx.x, L = t & 63;
    const int gu = blockIdx.x * 4 + (t >> 6);      // 0..1023
    const int l = gu >> 8, rem = gu & 255;
    const int c = rem >> 4, nt = rem & 15;
    const int h  = nt * 16 + (L & 15);
    const int k0 = c * 32 + (L >> 4) * 8;
    const float* src = W2 + (size_t)l * HD2 * HD;
    s8v v;
#pragma unroll
    for (int e = 0; e < 8; ++e)
        v[e] = (short)f2bf(src[(size_t)(k0 + e) * HD + h]);
    *(s8v*)(W2P + (size_t)gu * 512 + L * 8) = v;
}

// ---------------------------------------------------------------------------
// Fused GIN MLP v3: z = (agg @ W1 + b1).relu() @ W2 + b2, plus column stats.
//
// vs v2 (98 us): v2 was LDS-READ-BW bound — every one of 8 waves streamed
// the full 32KB W chunk as B-frags (512KB/CU/chunk; ~60 us of ds_read at
// 85 B/cyc). v3: 4 waves x 32 rows (mt=2) — each B-frag feeds 2 MFMAs, so
// W LDS traffic per row HALVES. Same counted-vmcnt pipeline (now 8 loads/
// wave/stage -> vmcnt(8)), same packed-W staging, same wave-private hchunk.
// LDS 76KB (64 W-dbuf + 10 hchunk + 2 bias) -> 2 blocks/CU.
// Regs ~240 (a[2][8]=64, acc2[2][16]=128 AGPR-eligible) -> 2 waves/SIMD.
// ---------------------------------------------------------------------------
__global__ __launch_bounds__(256, 2) void fused_mlp_kernel(
    const ushort_t* __restrict__ A,      // [NP, HD] bf16 (aggregate out)
    const ushort_t* __restrict__ W1l,    // [256 units x 512] packed bf16
    const float*    __restrict__ b1l,    // [HD2]
    const ushort_t* __restrict__ W2l,    // [256 units x 512] packed bf16
    const float*    __restrict__ b2l,    // [HD]
    ushort_t* __restrict__ C,            // [NP, HD] bf16 (pre-BN z)
    float* __restrict__ stats)           // [2*HD] col sum / sumsq (atomic)
{
    extern __shared__ char smem[];
    ushort_t* lds = (ushort_t*)smem;
    const int tid = threadIdx.x;
    const int w   = tid >> 6;            // wave 0..3 -> rows [w*32, w*32+32)
    const int L   = tid & 63;
    const int lm  = L & 15;
    const int q   = L >> 4;
    const int row0 = blockIdx.x * 128;

    // LDS map (bytes): 0..32767 buf0 | 32768..65535 buf1 |
    // 65536..75775 hchunk (4 x 2560) | 75776..77823 b1s.
    // Epilogue overlay: Cs 0..65535 | ssum 65536..69631 | ssq 69632..73727.
    float* b1s = (float*)(smem + 75776);
    char*  hcb = smem + 65536 + w * 2560;   // wave-private [32 rows][80B]

    // ---- biases -> LDS (consumed before the syncthreads drains vmcnt) ----
    b1s[tid]       = b1l[tid];
    b1s[256 + tid] = b1l[256 + tid];
    __syncthreads();

    // ---- A slice in registers: a[mt][kk], rows w*32 + mt*16 + lm ----
    s8v a[2][8];
#pragma unroll
    for (int mt = 0; mt < 2; ++mt) {
        const ushort_t* Arow = A + (size_t)(row0 + w * 32 + mt * 16 + lm) * HD;
#pragma unroll
        for (int kk = 0; kk < 8; ++kk)
            a[mt][kk] = *(const s8v*)(Arow + kk * 32 + q * 8);
    }
    __builtin_amdgcn_s_waitcnt(WAITCNT_VM0);   // a[] resident; vmcnt clean

    // stage chunk cc into buf: 32 contiguous 1KB units, 8 per wave.
    // buf layout (ushorts): W1c at +0 (16 units), W2c at +8192 (16 units).
    // Wave-uniform branch: waves 0-1 stage W1, waves 2-3 stage W2.
#define STAGE_W(buf, cc) do {                                                 \
    ushort_t* Wb_ = lds + (buf) * 16384;                                      \
    if (w < 2) {                                                              \
        _Pragma("unroll")                                                     \
        for (int i_ = 0; i_ < 8; ++i_) {                                      \
            const int u_ = w * 8 + i_;                                        \
            GLOAD_LDS16(W1l + ((cc) * 16 + u_) * 512 + L * 8,                 \
                        Wb_ + u_ * 512);                                      \
        }                                                                     \
    } else {                                                                  \
        _Pragma("unroll")                                                     \
        for (int i_ = 0; i_ < 8; ++i_) {                                      \
            const int u_ = (w - 2) * 8 + i_;                                  \
            GLOAD_LDS16(W2l + ((cc) * 16 + u_) * 512 + L * 8,                 \
                        Wb_ + 8192 + u_ * 512);                               \
        }                                                                     \
    }                                                                         \
} while (0)

    STAGE_W(0, 0);
    STAGE_W(1, 1);

    f4v acc2[2][16] = {};                // z rows (w*32 + mt*16 ..) x 256 cols
    for (int c = 0; c < 16; ++c) {
        // counted wait: stage(c) landed, stage(c+1)'s 8 loads stay in flight
        if (c < 15) __builtin_amdgcn_s_waitcnt(WAITCNT_VM8);
        else        __builtin_amdgcn_s_waitcnt(WAITCNT_VM0);
        __builtin_amdgcn_s_barrier();
        __builtin_amdgcn_sched_barrier(0);

        const ushort_t* Wb  = lds + (c & 1) * 16384;
        const ushort_t* W2b = Wb + 8192;

        // GEMM1: hchunk = A x W1c  (4 chains x 8 deep; B shared across mt)
        f4v acc1[2][2] = {};
        __builtin_amdgcn_s_setprio(1);
#pragma unroll
        for (int kk = 0; kk < 8; ++kk) {
#pragma unroll
            for (int nt = 0; nt < 2; ++nt) {
                s8v b = *(const s8v*)&Wb[(kk * 2 + nt) * 512 + L * 8];
                acc1[0][nt] = __builtin_amdgcn_mfma_f32_16x16x32_bf16(a[0][kk], b, acc1[0][nt], 0, 0, 0);
                acc1[1][nt] = __builtin_amdgcn_mfma_f32_16x16x32_bf16(a[1][kk], b, acc1[1][nt], 0, 0, 0);
            }
        }
        __builtin_amdgcn_s_setprio(0);

        // bias + relu + bf16 -> wave-private LDS [32][80B] (frag transpose)
#pragma unroll
        for (int mt = 0; mt < 2; ++mt) {
#pragma unroll
            for (int nt = 0; nt < 2; ++nt) {
                const float bj = b1s[c * 32 + nt * 16 + lm];
#pragma unroll
                for (int r = 0; r < 4; ++r) {
                    const int rr = mt * 16 + q * 4 + r;
                    *(ushort_t*)(hcb + rr * 80 + (nt * 16 + lm) * 2) =
                        f2bf(fmaxf(acc1[mt][nt][r] + bj, 0.f));
                }
            }
        }
        // GEMM2: zacc += hchunk x W2c  (32 independent chains; B shared)
        s8v at0 = *(const s8v*)(hcb + lm * 80 + q * 16);
        s8v at1 = *(const s8v*)(hcb + (16 + lm) * 80 + q * 16);
        __builtin_amdgcn_s_setprio(1);
#pragma unroll
        for (int nt = 0; nt < 16; ++nt) {
            s8v b = *(const s8v*)&W2b[nt * 512 + L * 8];
            acc2[0][nt] = __builtin_amdgcn_mfma_f32_16x16x32_bf16(at0, b, acc2[0][nt], 0, 0, 0);
            acc2[1][nt] = __builtin_amdgcn_mfma_f32_16x16x32_bf16(at1, b, acc2[1][nt], 0, 0, 0);
        }
        __builtin_amdgcn_s_setprio(0);

        __builtin_amdgcn_sched_barrier(0);
        __builtin_amdgcn_s_barrier();
        if (c + 2 < 16) STAGE_W((c & 1), c + 2);
    }
#undef STAGE_W

    __syncthreads();

    // ---- epilogue: bias + stats + bf16, LDS bounce for coalesced store ----
    ushort_t* Cs = lds;                      // [128][256] bf16, 64KB
    float* ssum  = (float*)(smem + 65536);   // [4][256]
    float* ssq   = (float*)(smem + 69632);   // [4][256]

#pragma unroll
    for (int nt = 0; nt < 16; ++nt) {
        const float bj = b2l[nt * 16 + lm];
        float s = 0.f, sq = 0.f;
#pragma unroll
        for (int mt = 0; mt < 2; ++mt) {
#pragma unroll
            for (int r = 0; r < 4; ++r) {
                const float f  = acc2[mt][nt][r] + bj;
                const int row  = w * 32 + mt * 16 + q * 4 + r;
                Cs[row * 256 + nt * 16 + lm] = f2bf(f);
                if (row0 + row < NN) { s += f; sq += f * f; }
            }
        }
        s  += __shfl_xor(s, 16, 64);  s  += __shfl_xor(s, 32, 64);
        sq += __shfl_xor(sq, 16, 64); sq += __shfl_xor(sq, 32, 64);
        if (q == 0) {
            ssum[w * 256 + nt * 16 + lm] = s;
            ssq [w * 256 + nt * 16 + lm] = sq;
        }
    }
    __syncthreads();

#pragma unroll
    for (int i = 0; i < 16; ++i) {
        const int idx = i * 256 + tid;       // 16B unit among 4096
        const int row = idx >> 5, ch = idx & 31;
        const s8v v = *(const s8v*)&Cs[idx * 8];
        *(s8v*)(C + (size_t)(row0 + row) * HD + ch * 8) = v;
    }
    {
        const float s  = ssum[tid] + ssum[256 + tid] + ssum[512 + tid] + ssum[768 + tid];
        const float sq = ssq[tid]  + ssq[256 + tid]  + ssq[512 + tid]  + ssq[768 + tid];
        unsafeAtomicAdd(&stats[tid], s);
        unsafeAtomicAdd(&stats[HD + tid], sq);
    }
}

// ---------------------------------------------------------------------------
// Batched transpose + fp32->bf16: out[z][c][r] = in[z][r][c]; blockIdx.z = batch.
__global__ __launch_bounds__(256) void transpose_cvt_kernel(
    const float* __restrict__ in, ushort_t* __restrict__ out, int R, int C,
    long inStride, long outStride)
{
    __shared__ float tile[32][33];
    const float* inp  = in  + (size_t)blockIdx.z * inStride;
    ushort_t*    outp = out + (size_t)blockIdx.z * outStride;
    const int bx = blockIdx.x * 32;
    const int by = blockIdx.y * 32;
    const int tx = threadIdx.x & 31;
    const int ty = threadIdx.x >> 5;
#pragma unroll
    for (int i = 0; i < 32; i += 8)
        tile[ty + i][tx] = inp[(size_t)(by + ty + i) * C + bx + tx];
    __syncthreads();
#pragma unroll
    for (int i = 0; i < 32; i += 8)
        outp[(size_t)(bx + ty + i) * R + by + tx] = f2bf(tile[tx][ty + i]);
}

__global__ __launch_bounds__(256) void cvt_kernel(
    const float* __restrict__ in, ushort_t* __restrict__ out, long n4)
{
    const long i = (long)blockIdx.x * 256 + threadIdx.x;
    if (i >= n4) return;
    const float4 v = ((const float4*)in)[i];
    ushort4 o;
    o.x = f2bf(v.x); o.y = f2bf(v.y); o.z = f2bf(v.z); o.w = f2bf(v.w);
    ((ushort4*)out)[i] = o;
}

__global__ __launch_bounds__(256) void zero_kernel(float* __restrict__ p, long n4)
{
    const long i = (long)blockIdx.x * 256 + threadIdx.x;
    if (i < n4) ((float4*)p)[i] = make_float4(0.f, 0.f, 0.f, 0.f);
}

// identity scale/shift + zeroed stats (once per call, before layer 0)
__global__ __launch_bounds__(256) void init_bn_kernel(
    float* __restrict__ sscale, float* __restrict__ sshift,
    float* __restrict__ stats)
{
    const int t = threadIdx.x;
    sscale[t] = 1.f;
    sshift[t] = 0.f;
    stats[t] = 0.f;
    stats[HD + t] = 0.f;
}

// scale/shift from stats; re-zero stats for the next layer
__global__ __launch_bounds__(256) void bnprep_kernel(
    float* __restrict__ stats, const float* __restrict__ gamma,
    const float* __restrict__ beta, float* __restrict__ sscale,
    float* __restrict__ sshift, int Nn)
{
    const int t = threadIdx.x;
    const float invN = 1.0f / (float)Nn;
    const float mu  = stats[t] * invN;
    const float var = stats[HD + t] * invN - mu * mu;
    const float inv = rsqrtf(var + BN_EPS);
    const float sc  = gamma[t] * inv;
    sscale[t] = sc;
    sshift[t] = beta[t] - mu * sc;
    stats[t] = 0.f;
    stats[HD + t] = 0.f;
}

// ---------------- CSR build (per call; edges are layer-invariant) -----------
__global__ __launch_bounds__(256) void hist_kernel(
    const int* __restrict__ dst, int* __restrict__ deg, int E)
{
    const int e = blockIdx.x * 256 + threadIdx.x;
    if (e < E) atomicAdd(&deg[dst[e]], 1);
}

__global__ __launch_bounds__(256) void scan1_kernel(
    const int* __restrict__ deg, int* __restrict__ partial,
    int* __restrict__ bsums, int n)
{
    __shared__ int tmp[256];
    const int i = blockIdx.x * 256 + threadIdx.x;
    const int v = (i < n) ? deg[i] : 0;
    tmp[threadIdx.x] = v;
    __syncthreads();
    for (int off = 1; off < 256; off <<= 1) {
        const int t = (threadIdx.x >= off) ? tmp[threadIdx.x - off] : 0;
        __syncthreads();
        tmp[threadIdx.x] += t;
        __syncthreads();
    }
    if (i < n) partial[i] = tmp[threadIdx.x] - v;
    if (threadIdx.x == 255) bsums[blockIdx.x] = tmp[255];
}

__global__ __launch_bounds__(512) void scan2_kernel(int* __restrict__ bsums, int nb)
{
    __shared__ int tmp[512];
    const int i = threadIdx.x;
    const int v = (i < nb) ? bsums[i] : 0;
    tmp[i] = v;
    __syncthreads();
    for (int off = 1; off < 512; off <<= 1) {
        const int t = (i >= off) ? tmp[i - off] : 0;
        __syncthreads();
        tmp[i] += t;
        __syncthreads();
    }
    if (i < nb) bsums[i] = tmp[i] - v;
}

__global__ __launch_bounds__(256) void scan3_kernel(
    const int* __restrict__ partial, const int* __restrict__ bsums,
    int* __restrict__ offs, int* __restrict__ cursor, int n)
{
    const int i = blockIdx.x * 256 + threadIdx.x;
    if (i < n) {
        const int o = partial[i] + bsums[blockIdx.x];
        offs[i] = o;
        cursor[i] = o;
    }
}

__global__ __launch_bounds__(256) void scatter_kernel(
    const int* __restrict__ src, const int* __restrict__ dst,
    int* __restrict__ cursor, int* __restrict__ srcSorted, int E)
{
    const int e = blockIdx.x * 256 + threadIdx.x;
    if (e >= E) return;
    const int p = atomicAdd(&cursor[dst[e]], 1);
    srcSorted[p] = src[e];
}

// ---------------------------------------------------------------------------
// out[n] = bf16( (1+eps)*y[n] + sum_{s in nbrs(n)} y[s] ),
// y[i] = relu( z[i]*sscale + sshift )  (BN on the fly).
__global__ __launch_bounds__(256) void aggregate_kernel(
    const ushort_t* __restrict__ z, const int* __restrict__ offs,
    const int* __restrict__ deg, const int* __restrict__ srcSorted,
    const float* __restrict__ epsArr, int epsIdx,
    const float* __restrict__ sscale, const float* __restrict__ sshift,
    ushort_t* __restrict__ out)
{
    const int n = blockIdx.x * 8 + (threadIdx.x >> 5);   // 8 nodes / 256 thr
    const int L = threadIdx.x & 31;
    const int c0 = L * 8;
    const float4 scA = *(const float4*)(sscale + c0);
    const float4 scB = *(const float4*)(sscale + c0 + 4);
    const float4 shA = *(const float4*)(sshift + c0);
    const float4 shB = *(const float4*)(sshift + c0 + 4);
    const int start = offs[n];
    const int dc = deg[n];
    float a[8] = {};
    float b[8] = {};
    int j = 0;
    for (; j + 1 < dc; j += 2) {
        const int s0 = srcSorted[start + j];
        const int s1 = srcSorted[start + j + 1];
        const uint4 u = *(const uint4*)(z + (size_t)s0 * HD + c0);
        const uint4 v = *(const uint4*)(z + (size_t)s1 * HD + c0);
        a[0] += fmaxf(blo(u.x) * scA.x + shA.x, 0.f);
        a[1] += fmaxf(bhi(u.x) * scA.y + shA.y, 0.f);
        a[2] += fmaxf(blo(u.y) * scA.z + shA.z, 0.f);
        a[3] += fmaxf(bhi(u.y) * scA.w + shA.w, 0.f);
        a[4] += fmaxf(blo(u.z) * scB.x + shB.x, 0.f);
        a[5] += fmaxf(bhi(u.z) * scB.y + shB.y, 0.f);
        a[6] += fmaxf(blo(u.w) * scB.z + shB.z, 0.f);
        a[7] += fmaxf(bhi(u.w) * scB.w + shB.w, 0.f);
        b[0] += fmaxf(blo(v.x) * scA.x + shA.x, 0.f);
        b[1] += fmaxf(bhi(v.x) * scA.y + shA.y, 0.f);
        b[2] += fmaxf(blo(v.y) * scA.z + shA.z, 0.f);
        b[3] += fmaxf(bhi(v.y) * scA.w + shA.w, 0.f);
        b[4] += fmaxf(blo(v.z) * scB.x + shB.x, 0.f);
        b[5] += fmaxf(bhi(v.z) * scB.y + shB.y, 0.f);
        b[6] += fmaxf(blo(v.w) * scB.z + shB.z, 0.f);
        b[7] += fmaxf(bhi(v.w) * scB.w + shB.w, 0.f);
    }
    if (j < dc) {
        const int s0 = srcSorted[start + j];
        const uint4 u = *(const uint4*)(z + (size_t)s0 * HD + c0);
        a[0] += fmaxf(blo(u.x) * scA.x + shA.x, 0.f);
        a[1] += fmaxf(bhi(u.x) * scA.y + shA.y, 0.f);
        a[2] += fmaxf(blo(u.y) * scA.z + shA.z, 0.f);
        a[3] += fmaxf(bhi(u.y) * scA.w + shA.w, 0.f);
        a[4] += fmaxf(blo(u.z) * scB.x + shB.x, 0.f);
        a[5] += fmaxf(bhi(u.z) * scB.y + shB.y, 0.f);
        a[6] += fmaxf(blo(u.w) * scB.z + shB.z, 0.f);
        a[7] += fmaxf(bhi(u.w) * scB.w + shB.w, 0.f);
    }
#pragma unroll
    for (int k = 0; k < 8; ++k) a[k] += b[k];
    const float se = 1.0f + epsArr[epsIdx];
    const uint4 hs = *(const uint4*)(z + (size_t)n * HD + c0);
    float y[8];
    y[0] = se * fmaxf(blo(hs.x) * scA.x + shA.x, 0.f) + a[0];
    y[1] = se * fmaxf(bhi(hs.x) * scA.y + shA.y, 0.f) + a[1];
    y[2] = se * fmaxf(blo(hs.y) * scA.z + shA.z, 0.f) + a[2];
    y[3] = se * fmaxf(bhi(hs.y) * scA.w + shA.w, 0.f) + a[3];
    y[4] = se * fmaxf(blo(hs.z) * scB.x + shB.x, 0.f) + a[4];
    y[5] = se * fmaxf(bhi(hs.z) * scB.y + shB.y, 0.f) + a[5];
    y[6] = se * fmaxf(blo(hs.w) * scB.z + shB.z, 0.f) + a[6];
    y[7] = se * fmaxf(bhi(hs.w) * scB.w + shB.w, 0.f) + a[7];
    uint4 o;
    o.x = (unsigned)f2bf(y[0]) | ((unsigned)f2bf(y[1]) << 16);
    o.y = (unsigned)f2bf(y[2]) | ((unsigned)f2bf(y[3]) << 16);
    o.z = (unsigned)f2bf(y[4]) | ((unsigned)f2bf(y[5]) << 16);
    o.w = (unsigned)f2bf(y[6]) | ((unsigned)f2bf(y[7]) << 16);
    *(uint4*)(out + (size_t)n * HD + c0) = o;
}

// ---------------------------------------------------------------------------
// Fused mean-pool + head, BN on the fly.
__global__ __launch_bounds__(256) void pool_head_kernel(
    const ushort_t* __restrict__ z, const int* __restrict__ batch,
    const float* __restrict__ sscale, const float* __restrict__ sshift,
    const float* __restrict__ Wp1, const float* __restrict__ bp1,
    const float* __restrict__ Wp2, const float* __restrict__ bp2,
    float* __restrict__ out)
{
    __shared__ float poolw[4][HD];
    __shared__ float pool[HD];
    __shared__ float red[128];
    __shared__ int seg[2];
    const int g = blockIdx.x;
    const int t = threadIdx.x;
    const int w = t >> 6;
    const int L = t & 63;
    if (t == 0) {
        int lo = 0, hi = NN;
        while (lo < hi) { const int m = (lo + hi) >> 1; if (batch[m] < g) lo = m + 1; else hi = m; }
        seg[0] = lo;
        hi = NN;
        while (lo < hi) { const int m = (lo + hi) >> 1; if (batch[m] < g + 1) lo = m + 1; else hi = m; }
        seg[1] = lo;
    }
    __syncthreads();
    const int start = seg[0], end = seg[1];
    const int c0 = L * 4;
    const float4 sc = *(const float4*)(sscale + c0);
    const float4 sh = *(const float4*)(sshift + c0);
    float a0 = 0.f, a1 = 0.f, a2 = 0.f, a3 = 0.f;
    float b0 = 0.f, b1 = 0.f, b2 = 0.f, b3 = 0.f;
    int r = start + w;
    for (; r + 4 < end; r += 8) {
        const ushort4 u = *(const ushort4*)(z + (size_t)r * HD + c0);
        const ushort4 v = *(const ushort4*)(z + (size_t)(r + 4) * HD + c0);
        a0 += fmaxf(bf2f(u.x) * sc.x + sh.x, 0.f);
        a1 += fmaxf(bf2f(u.y) * sc.y + sh.y, 0.f);
        a2 += fmaxf(bf2f(u.z) * sc.z + sh.z, 0.f);
        a3 += fmaxf(bf2f(u.w) * sc.w + sh.w, 0.f);
        b0 += fmaxf(bf2f(v.x) * sc.x + sh.x, 0.f);
        b1 += fmaxf(bf2f(v.y) * sc.y + sh.y, 0.f);
        b2 += fmaxf(bf2f(v.z) * sc.z + sh.z, 0.f);
        b3 += fmaxf(bf2f(v.w) * sc.w + sh.w, 0.f);
    }
    if (r < end) {
        const ushort4 u = *(const ushort4*)(z + (size_t)r * HD + c0);
        a0 += fmaxf(bf2f(u.x) * sc.x + sh.x, 0.f);
        a1 += fmaxf(bf2f(u.y) * sc.y + sh.y, 0.f);
        a2 += fmaxf(bf2f(u.z) * sc.z + sh.z, 0.f);
        a3 += fmaxf(bf2f(u.w) * sc.w + sh.w, 0.f);
    }
    poolw[w][c0 + 0] = a0 + b0;
    poolw[w][c0 + 1] = a1 + b1;
    poolw[w][c0 + 2] = a2 + b2;
    poolw[w][c0 + 3] = a3 + b3;
    __syncthreads();
    const float invC = 1.0f / (float)max(end - start, 1);
    pool[t] = (poolw[0][t] + poolw[1][t] + poolw[2][t] + poolw[3][t]) * invC;
    __syncthreads();
    if (t < 128) {
        float acc = 0.f;
#pragma unroll 4
        for (int k = 0; k < HD; ++k)
            acc += pool[k] * Wp1[k * 128 + t];
        red[t] = fmaxf(acc + bp1[t], 0.f) * Wp2[t];
    }
    __syncthreads();
    for (int sft = 64; sft > 0; sft >>= 1) {
        if (t < sft) red[t] += red[t + sft];
        __syncthreads();
    }
    if (t == 0) out[g] = red[0] + bp2[0];
}

// ---------------------------------------------------------------------------
extern "C" void kernel_launch(void* const* d_in, const int* in_sizes, int n_in,
                              void* d_out, int out_size, void* d_ws, size_t ws_size,
                              hipStream_t stream)
{
    const float* x     = (const float*)d_in[0];
    const int*   ei    = (const int*)  d_in[1];
    const int*   batch = (const int*)  d_in[2];
    const float* W_in  = (const float*)d_in[3];
    const float* b_in  = (const float*)d_in[4];
    const float* eps   = (const float*)d_in[5];
    const float* W1    = (const float*)d_in[6];
    const float* b1    = (const float*)d_in[7];
    const float* W2    = (const float*)d_in[8];
    const float* b2    = (const float*)d_in[9];
    const float* gamma = (const float*)d_in[10];
    const float* beta  = (const float*)d_in[11];
    const float* Wp1   = (const float*)d_in[12];
    const float* bp1   = (const float*)d_in[13];
    const float* Wp2   = (const float*)d_in[14];
    const float* bp2   = (const float*)d_in[15];

    const int* srcIdx = ei;
    const int* dstIdx = ei + EE;

    // ---- workspace layout ----
    char* p = (char*)d_ws;
    ushort_t* zbuf    = (ushort_t*)p;  p += (size_t)NP * HD  * 2;   // pre-BN acts
    ushort_t* abuf    = (ushort_t*)p;  p += (size_t)NP * HD  * 2;   // aggregate out
    ushort_t* hidden  = (ushort_t*)p;  p += (size_t)NP * HD2 * 2;   // x_bf alias (GEMM0 A)
    ushort_t* W1P     = (ushort_t*)p;  p += (size_t)NL * HD2 * HD * 2;   // packed
    ushort_t* W2P     = (ushort_t*)p;  p += (size_t)NL * HD * HD2 * 2;   // packed
    ushort_t* WinT    = (ushort_t*)p;  p += (size_t)HD * DIN * 2;
    int* deg          = (int*)p;       p += (size_t)NN * 4;
    int* partial      = (int*)p;       p += (size_t)NN * 4;
    int* bsums        = (int*)p;       p += 512 * 4;
    int* offs         = (int*)p;       p += (size_t)NN * 4;
    int* cursor       = (int*)p;       p += (size_t)NN * 4;
    int* srcSorted    = (int*)p;       p += (size_t)EE * 4;
    float* stats      = (float*)p;     p += 2 * HD * 4;
    float* sscale     = (float*)p;     p += HD * 4;
    float* sshift     = (float*)p;     p += HD * 4;
    ushort_t* x_bf    = hidden;        // GEMM0 A

    const int nb = (NN + 255) / 256;   // 391
    const int GEMM_LDS  = 53248;       // gemm_bf16: 3 x 16KB stages + 4KB stats
    const int FUSED_LDS = 77824;       // fused_mlp v3: 2x32KB W + 10KB hchunk + 2KB bias

    // ---- BN identity + stats zero ----
    init_bn_kernel<<<1, 256, 0, stream>>>(sscale, sshift, stats);

    // ---- weight conversion (Win transposed bf16; W1/W2 packed frag-order) --
    transpose_cvt_kernel<<<dim3(HD / 32, DIN / 32, 1), 256, 0, stream>>>(
        W_in, WinT, DIN, HD, 0, 0);
    pack_w1_kernel<<<256, 256, 0, stream>>>(W1, W1P);
    pack_w2_kernel<<<256, 256, 0, stream>>>(W2, W2P);
    cvt_kernel<<<(int)(((long)NN * DIN / 4 + 255) / 256), 256, 0, stream>>>(
        x, x_bf, (long)NN * DIN / 4);

    // ---- CSR build (once; edges layer-invariant) ----
    zero_kernel<<<(NN / 4 + 255) / 256, 256, 0, stream>>>((float*)deg, NN / 4);
    hist_kernel<<<(EE + 255) / 256, 256, 0, stream>>>(dstIdx, deg, EE);
    scan1_kernel<<<nb, 256, 0, stream>>>(deg, partial, bsums, NN);
    scan2_kernel<<<1, 512, 0, stream>>>(bsums, nb);
    scan3_kernel<<<nb, 256, 0, stream>>>(partial, bsums, offs, cursor, NN);
    scatter_kernel<<<(EE + 255) / 256, 256, 0, stream>>>(srcIdx, dstIdx, cursor, srcSorted, EE);

    // ---- input projection: zbuf = relu(x @ W_in + b_in)  (identity BN) ----
    gemm_bf16<<<dim3(NP / 128, HD / 128), 256, GEMM_LDS, stream>>>(
        x_bf, DIN, WinT, DIN, b_in, zbuf, HD, DIN, 1, 0, nullptr, 0);

    // ---- GIN layers: aggregate -> fused MLP (+stats) -> BN prep ----
    for (int l = 0; l < NL; ++l) {
        aggregate_kernel<<<NN / 8, 256, 0, stream>>>(
            zbuf, offs, deg, srcSorted, eps, l, sscale, sshift, abuf);

        fused_mlp_kernel<<<NP / 128, 256, FUSED_LDS, stream>>>(
            abuf, W1P + (size_t)l * HD2 * HD, b1 + (size_t)l * HD2,
            W2P + (size_t)l * HD * HD2, b2 + (size_t)l * HD, zbuf, stats);

        bnprep_kernel<<<1, 256, 0, stream>>>(
            stats, gamma + (size_t)l * HD, beta + (size_t)l * HD, sscale, sshift, NN);
    }

    // ---- fused mean pool + head (BN on the fly) ----
    pool_head_kernel<<<NG, 256, 0, stream>>>(zbuf, batch, sscale, sshift,
                                             Wp1, bp1, Wp2, bp2, (float*)d_out);
}